// Round 1
// baseline (548.958 us; speedup 1.0000x reference)
//
#include <hip/hip_runtime.h>
#include <hip/hip_bf16.h>
#include <math.h>

// Problem constants
#define Bn    64
#define Cn    3
#define IMG   224
#define C1    6      // conv1 out channels
#define C2    16     // conv2 out channels
#define P1    110    // after conv1(220) + maxpool2 -> 110
#define P2    106    // conv2 output spatial (110-5+1)
#define NPOS  (P1*P1)        // 12100
#define NVALID (P2*P2)       // 11236
#define Hh    32
#define Ww    64
#define UPR   10
#define UPT   10
#define Hg    (Hh*UPR)       // 320
#define Wg    (Ww*UPT)       // 640
#define POOLED_SIZE (Bn*Cn*Hh*Ww)   // 393216

// -------------------------------------------------------------------------
// K1: fused conv1 (5x5 VALID) + maxpool2 + 25 window box-sums.
// One block per (b, oc): computes the 110x110 pooled image into LDS, then
// windowsum[ky][kx] = sum over the 106x106 window at offset (ky,kx).
// -------------------------------------------------------------------------
__global__ __launch_bounds__(256) void k1_conv1_pool_wsum(
    const float* __restrict__ x,      // (B,3,224,224)
    const float* __restrict__ w1,     // (6,3,5,5)
    const float* __restrict__ b1,     // (6,)
    float* __restrict__ wsum)         // (B,6,25)
{
    __shared__ float img[NPOS];       // 48.4 KB
    __shared__ float wlds[75];
    __shared__ float rs[P1 * 5];      // per-row sums for 5 kx offsets

    const int bic = blockIdx.x;       // 0..383
    const int b = bic / C1;
    const int oc = bic % C1;
    const int tid = threadIdx.x;

    if (tid < 75) wlds[tid] = w1[oc * 75 + tid];
    __syncthreads();

    const float bias = b1[oc];
    const float* xb = x + (size_t)b * Cn * IMG * IMG;

    for (int pos = tid; pos < NPOS; pos += 256) {
        const int py = pos / P1;
        const int px = pos % P1;
        const int iy0 = 2 * py;
        const int ix0 = 2 * px;
        float a00 = bias, a01 = bias, a10 = bias, a11 = bias;
        #pragma unroll
        for (int ic = 0; ic < 3; ++ic) {
            const float* xp = xb + ic * IMG * IMG + iy0 * IMG + ix0;
            float win[6][6];
            #pragma unroll
            for (int r = 0; r < 6; ++r)
                #pragma unroll
                for (int c = 0; c < 6; ++c)
                    win[r][c] = xp[r * IMG + c];
            const float* wp = wlds + ic * 25;
            #pragma unroll
            for (int ky = 0; ky < 5; ++ky)
                #pragma unroll
                for (int kx = 0; kx < 5; ++kx) {
                    const float wv = wp[ky * 5 + kx];
                    a00 += win[ky][kx]     * wv;
                    a01 += win[ky][kx+1]   * wv;
                    a10 += win[ky+1][kx]   * wv;
                    a11 += win[ky+1][kx+1] * wv;
                }
        }
        img[pos] = fmaxf(fmaxf(a00, a01), fmaxf(a10, a11));
    }
    __syncthreads();

    // Per-row windowed sums: rs[y][kx] = sum_{x=kx}^{kx+105} img[y][x]
    if (tid < P1) {
        const float* row = img + tid * P1;
        float full = 0.0f;
        for (int xq = 0; xq < P1; ++xq) full += row[xq];
        float pre = 0.0f;
        #pragma unroll
        for (int kx = 0; kx < 5; ++kx) {
            float suf = 0.0f;
            for (int xq = kx + P2; xq < P1; ++xq) suf += row[xq];
            rs[tid * 5 + kx] = full - pre - suf;
            pre += row[kx];
        }
    }
    __syncthreads();

    // windowsum[ky][kx] = sum_{y=ky}^{ky+105} rs[y][kx]
    if (tid < 25) {
        const int ky = tid / 5;
        const int kx = tid % 5;
        float s = 0.0f;
        for (int y = ky; y < ky + P2; ++y) s += rs[y * 5 + kx];
        wsum[bic * 25 + tid] = s;
    }
}

// -------------------------------------------------------------------------
// K2: head — feat = b2 + (W2 . wsum)/11236 ; fc1+relu ; fc2+sigmoid*5.
// One block (64 threads) per batch element.
// -------------------------------------------------------------------------
__global__ __launch_bounds__(64) void k2_head(
    const float* __restrict__ wsum,   // (B,6,25) = (B,150)
    const float* __restrict__ w2,     // (16,150)
    const float* __restrict__ b2,     // (16,)
    const float* __restrict__ fc1w,   // (8,16)
    const float* __restrict__ fc1b,   // (8,)
    const float* __restrict__ fc2w,   // (2,8)
    const float* __restrict__ fc2b,   // (2,)
    float* __restrict__ wt_ws,        // (B,2) workspace copy
    float* __restrict__ out)          // d_out; weight at POOLED_SIZE
{
    const int b = blockIdx.x;
    const int tid = threadIdx.x;
    __shared__ float sfeat[16];
    __shared__ float sh[8];

    const float* wsb = wsum + b * 150;
    if (tid < 16) {
        float s = 0.0f;
        for (int j = 0; j < 150; ++j) s += w2[tid * 150 + j] * wsb[j];
        sfeat[tid] = b2[tid] + s * (1.0f / (float)NVALID);
    }
    __syncthreads();
    if (tid < 8) {
        float s = fc1b[tid];
        #pragma unroll
        for (int j = 0; j < 16; ++j) s += fc1w[tid * 16 + j] * sfeat[j];
        sh[tid] = fmaxf(s, 0.0f);
    }
    __syncthreads();
    if (tid < 2) {
        float s = fc2b[tid];
        #pragma unroll
        for (int j = 0; j < 8; ++j) s += fc2w[tid * 8 + j] * sh[j];
        // numerically stable sigmoid
        float sig = (s >= 0.0f) ? (1.0f / (1.0f + expf(-s)))
                                : (expf(s) / (1.0f + expf(s)));
        const float wgt = 5.0f * sig;
        wt_ws[b * 2 + tid] = wgt;
        out[POOLED_SIZE + b * 2 + tid] = wgt;
    }
}

// -------------------------------------------------------------------------
// K3: log-polar grid sample (border, bilinear) + 10x10 average pool.
// One block per (b, h). 640 threads = one per gx column; each thread handles
// the 10 gy rows of this h-slab, accumulating 3 channels; LDS reduce over
// the 10 gx columns per output w.
// -------------------------------------------------------------------------
__global__ __launch_bounds__(640) void k3_sample_pool(
    const float* __restrict__ x,      // (B,3,224,224)
    const float* __restrict__ ltp,    // (B,2)
    const float* __restrict__ wt,     // (B,2)
    float* __restrict__ out)          // pooled at offset 0
{
    __shared__ float part[3 * Wg];    // 7.7 KB

    const int h = blockIdx.x;         // 0..31
    const int b = blockIdx.y;         // 0..63
    const int tid = threadIdx.x;      // gx 0..639

    const float w0 = wt[b * 2 + 0];
    const float w1 = wt[b * 2 + 1];
    const float l0 = ltp[b * 2 + 0];
    const float l1 = ltp[b * 2 + 1];
    const float start = logf(0.01f * w0);
    const float stop  = logf(0.6f  * w1);
    const float dr = stop - start;

    const float angle = 6.283185307179586f * (float)tid / (float)Wg;
    const float sn = sinf(angle);
    const float cs = cosf(angle);

    const float* xb = x + (size_t)b * Cn * IMG * IMG;

    float acc0 = 0.0f, acc1 = 0.0f, acc2 = 0.0f;
    #pragma unroll
    for (int i = 0; i < UPR; ++i) {
        const int gy = h * UPR + i;
        const float t = (float)gy / (float)(Hg - 1);
        const float r = expf(start + dr * t);
        const float gxn = r * sn + l0;   // grid[...,0]
        const float gyn = r * cs + l1;   // grid[...,1]
        const float ix = ((gxn + 1.0f) * (float)IMG - 1.0f) * 0.5f;
        const float iy = ((gyn + 1.0f) * (float)IMG - 1.0f) * 0.5f;
        const float x0f = floorf(ix);
        const float y0f = floorf(iy);
        const float wx = ix - x0f;
        const float wy = iy - y0f;
        int x0 = (int)x0f, y0 = (int)y0f;
        int x1 = x0 + 1,   y1 = y0 + 1;
        x0 = min(max(x0, 0), IMG - 1);
        x1 = min(max(x1, 0), IMG - 1);
        y0 = min(max(y0, 0), IMG - 1);
        y1 = min(max(y1, 0), IMG - 1);
        const float w00 = (1.0f - wx) * (1.0f - wy);
        const float w01 = wx * (1.0f - wy);
        const float w10 = (1.0f - wx) * wy;
        const float w11 = wx * wy;
        const int o00 = y0 * IMG + x0;
        const int o01 = y0 * IMG + x1;
        const int o10 = y1 * IMG + x0;
        const int o11 = y1 * IMG + x1;
        {
            const float* xc = xb;
            acc0 += xc[o00]*w00 + xc[o01]*w01 + xc[o10]*w10 + xc[o11]*w11;
        }
        {
            const float* xc = xb + IMG * IMG;
            acc1 += xc[o00]*w00 + xc[o01]*w01 + xc[o10]*w10 + xc[o11]*w11;
        }
        {
            const float* xc = xb + 2 * IMG * IMG;
            acc2 += xc[o00]*w00 + xc[o01]*w01 + xc[o10]*w10 + xc[o11]*w11;
        }
    }
    part[0 * Wg + tid] = acc0;
    part[1 * Wg + tid] = acc1;
    part[2 * Wg + tid] = acc2;
    __syncthreads();

    if (tid < Cn * Ww) {
        const int c = tid / Ww;
        const int w = tid % Ww;
        const float* p = part + c * Wg + w * UPT;
        float s = 0.0f;
        #pragma unroll
        for (int j = 0; j < UPT; ++j) s += p[j];
        out[(((size_t)b * Cn + c) * Hh + h) * Ww + w] = s * (1.0f / (UPR * UPT));
    }
}

// -------------------------------------------------------------------------
extern "C" void kernel_launch(void* const* d_in, const int* in_sizes, int n_in,
                              void* d_out, int out_size, void* d_ws, size_t ws_size,
                              hipStream_t stream) {
    const float* x       = (const float*)d_in[0];
    const float* ltp     = (const float*)d_in[1];
    const float* conv1_w = (const float*)d_in[2];
    const float* conv1_b = (const float*)d_in[3];
    const float* conv2_w = (const float*)d_in[4];
    const float* conv2_b = (const float*)d_in[5];
    const float* fc1_w   = (const float*)d_in[6];
    const float* fc1_b   = (const float*)d_in[7];
    const float* fc2_w   = (const float*)d_in[8];
    const float* fc2_b   = (const float*)d_in[9];
    float* out = (float*)d_out;

    // workspace layout: wsum (B*6*25 floats) | weight (B*2 floats)
    float* wsum  = (float*)d_ws;
    float* wt_ws = wsum + Bn * C1 * 25;

    k1_conv1_pool_wsum<<<dim3(Bn * C1), dim3(256), 0, stream>>>(x, conv1_w, conv1_b, wsum);
    k2_head<<<dim3(Bn), dim3(64), 0, stream>>>(wsum, conv2_w, conv2_b,
                                               fc1_w, fc1_b, fc2_w, fc2_b,
                                               wt_ws, out);
    k3_sample_pool<<<dim3(Hh, Bn), dim3(Wg), 0, stream>>>(x, ltp, wt_ws, out);
}

// Round 2
// 378.235 us; speedup vs baseline: 1.4514x; 1.4514x over previous
//
#include <hip/hip_runtime.h>
#include <hip/hip_bf16.h>
#include <math.h>

// Problem constants
#define Bn    64
#define Cn    3
#define IMG   224
#define C1    6      // conv1 out channels
#define P1    110    // after conv1(220) + maxpool2 -> 110
#define P2    106    // conv2 output spatial (110-5+1)
#define NVALID (P2*P2)       // 11236
#define Hh    32
#define Ww    64
#define UPR   10
#define UPT   10
#define Hg    (Hh*UPR)       // 320
#define Wg    (Ww*UPT)       // 640
#define POOLED_SIZE (Bn*Cn*Hh*Ww)   // 393216
#define RPB   4              // pooled rows per block (1 per wave)

// -------------------------------------------------------------------------
// K1: fused conv1 (5x5 VALID, all 6 OCs) + maxpool2 + row window sums +
// atomic accumulate into the 25 conv2-window box-sums.
// Block = 256 threads = 4 waves; wave handles one pooled row (y0+wid).
// Lane l (<55) computes pooled pixels (2l, 2l+1) for all 6 OCs from a
// shared 6x8 input window held in registers (VALU-bound: 3600 FMA/lane).
// -------------------------------------------------------------------------
__global__ __launch_bounds__(256) void k1_fused(
    const float* __restrict__ x,      // (B,3,224,224)
    const float* __restrict__ w1,     // (6,3,5,5) = 450
    const float* __restrict__ b1,     // (6,)
    float* __restrict__ wsum)         // (B,6,25) pre-zeroed, atomically accumulated
{
    __shared__ __attribute__((aligned(16))) float xs[3][12][224];  // 32256 B
    __shared__ float wlds[450];                                    // 1800 B
    __shared__ float rowbuf[RPB][C1][112];                         // 10752 B

    const int b    = blockIdx.y;
    const int y0   = blockIdx.x * RPB;
    const int tid  = threadIdx.x;
    const int wid  = tid >> 6;
    const int lane = tid & 63;

    for (int i = tid; i < 450; i += 256) wlds[i] = w1[i];

    const float* xb = x + (size_t)b * (Cn * IMG * IMG);
    const int gybase = 2 * y0;

    // stage 12 input rows x 3 ic, coalesced float4
    for (int i = tid; i < 3 * 12 * 56; i += 256) {
        const int ic  = i / (12 * 56);
        const int rem = i % (12 * 56);
        const int r   = rem / 56;
        const int c4  = rem % 56;
        const int gy  = gybase + r;
        if (gy < IMG) {
            const float4 v = *(const float4*)(xb + ic * IMG * IMG + gy * IMG + c4 * 4);
            *(float4*)(&xs[ic][r][c4 * 4]) = v;
        }
    }
    __syncthreads();

    const int y = y0 + wid;
    const bool active = (lane < 55) && (y < P1);

    if (active) {
        float acc[C1][8];
        #pragma unroll
        for (int oc = 0; oc < C1; ++oc) {
            const float bv = b1[oc];
            #pragma unroll
            for (int j = 0; j < 8; ++j) acc[oc][j] = bv;
        }

        #pragma unroll
        for (int ic = 0; ic < 3; ++ic) {
            float win[6][8];
            #pragma unroll
            for (int r = 0; r < 6; ++r) {
                const float4 a = *(const float4*)&xs[ic][2 * wid + r][4 * lane];
                const float4 c = *(const float4*)&xs[ic][2 * wid + r][4 * lane + 4];
                win[r][0] = a.x; win[r][1] = a.y; win[r][2] = a.z; win[r][3] = a.w;
                win[r][4] = c.x; win[r][5] = c.y; win[r][6] = c.z; win[r][7] = c.w;
            }
            #pragma unroll
            for (int oc = 0; oc < C1; ++oc) {
                const float* wp = wlds + (oc * 3 + ic) * 25;
                #pragma unroll
                for (int ky = 0; ky < 5; ++ky) {
                    #pragma unroll
                    for (int kx = 0; kx < 5; ++kx) {
                        const float wv = wp[ky * 5 + kx];
                        acc[oc][0] += win[ky    ][kx    ] * wv;
                        acc[oc][1] += win[ky    ][kx + 1] * wv;
                        acc[oc][2] += win[ky    ][kx + 2] * wv;
                        acc[oc][3] += win[ky    ][kx + 3] * wv;
                        acc[oc][4] += win[ky + 1][kx    ] * wv;
                        acc[oc][5] += win[ky + 1][kx + 1] * wv;
                        acc[oc][6] += win[ky + 1][kx + 2] * wv;
                        acc[oc][7] += win[ky + 1][kx + 3] * wv;
                    }
                }
            }
        }

        #pragma unroll
        for (int oc = 0; oc < C1; ++oc) {
            const float p0 = fmaxf(fmaxf(acc[oc][0], acc[oc][1]),
                                   fmaxf(acc[oc][4], acc[oc][5]));
            const float p1 = fmaxf(fmaxf(acc[oc][2], acc[oc][3]),
                                   fmaxf(acc[oc][6], acc[oc][7]));
            rowbuf[wid][oc][2 * lane]     = p0;
            rowbuf[wid][oc][2 * lane + 1] = p1;
        }
    }
    __syncthreads();

    // rs[oc][kx] = windowed row sum; scatter into windowsum bins (atomic).
    if (lane < 30 && y < P1) {
        const int oc = lane / 5;
        const int kx = lane % 5;
        const float* rp = rowbuf[wid][oc];
        float s = 0.0f;
        for (int xq = kx; xq < kx + P2; ++xq) s += rp[xq];
        const int kylo = (y - 105 > 0) ? (y - 105) : 0;
        const int kyhi = (y < 4) ? y : 4;
        float* wp = wsum + ((size_t)b * C1 + oc) * 25 + kx;
        for (int ky = kylo; ky <= kyhi; ++ky)
            atomicAdd(wp + ky * 5, s);
    }
}

// -------------------------------------------------------------------------
// K2: head — feat = b2 + (W2 . wsum)/11236 ; fc1+relu ; fc2+sigmoid*5.
// -------------------------------------------------------------------------
__global__ __launch_bounds__(64) void k2_head(
    const float* __restrict__ wsum,   // (B,6,25) = (B,150)
    const float* __restrict__ w2,     // (16,150)
    const float* __restrict__ b2,     // (16,)
    const float* __restrict__ fc1w,   // (8,16)
    const float* __restrict__ fc1b,   // (8,)
    const float* __restrict__ fc2w,   // (2,8)
    const float* __restrict__ fc2b,   // (2,)
    float* __restrict__ wt_ws,        // (B,2) workspace copy
    float* __restrict__ out)          // d_out; weight at POOLED_SIZE
{
    const int b = blockIdx.x;
    const int tid = threadIdx.x;
    __shared__ float sfeat[16];
    __shared__ float sh[8];

    const float* wsb = wsum + b * 150;
    if (tid < 16) {
        float s = 0.0f;
        for (int j = 0; j < 150; ++j) s += w2[tid * 150 + j] * wsb[j];
        sfeat[tid] = b2[tid] + s * (1.0f / (float)NVALID);
    }
    __syncthreads();
    if (tid < 8) {
        float s = fc1b[tid];
        #pragma unroll
        for (int j = 0; j < 16; ++j) s += fc1w[tid * 16 + j] * sfeat[j];
        sh[tid] = fmaxf(s, 0.0f);
    }
    __syncthreads();
    if (tid < 2) {
        float s = fc2b[tid];
        #pragma unroll
        for (int j = 0; j < 8; ++j) s += fc2w[tid * 8 + j] * sh[j];
        float sig = (s >= 0.0f) ? (1.0f / (1.0f + expf(-s)))
                                : (expf(s) / (1.0f + expf(s)));
        const float wgt = 5.0f * sig;
        wt_ws[b * 2 + tid] = wgt;
        out[POOLED_SIZE + b * 2 + tid] = wgt;
    }
}

// -------------------------------------------------------------------------
// K3: log-polar grid sample (border, bilinear) + 10x10 average pool.
// One block per (b, h). 640 threads = one per gx column.
// -------------------------------------------------------------------------
__global__ __launch_bounds__(640) void k3_sample_pool(
    const float* __restrict__ x,      // (B,3,224,224)
    const float* __restrict__ ltp,    // (B,2)
    const float* __restrict__ wt,     // (B,2)
    float* __restrict__ out)          // pooled at offset 0
{
    __shared__ float part[3 * Wg];    // 7.7 KB

    const int h = blockIdx.x;         // 0..31
    const int b = blockIdx.y;         // 0..63
    const int tid = threadIdx.x;      // gx 0..639

    const float w0 = wt[b * 2 + 0];
    const float w1 = wt[b * 2 + 1];
    const float l0 = ltp[b * 2 + 0];
    const float l1 = ltp[b * 2 + 1];
    const float start = logf(0.01f * w0);
    const float stop  = logf(0.6f  * w1);
    const float dr = stop - start;

    const float angle = 6.283185307179586f * (float)tid / (float)Wg;
    const float sn = sinf(angle);
    const float cs = cosf(angle);

    const float* xb = x + (size_t)b * Cn * IMG * IMG;

    float acc0 = 0.0f, acc1 = 0.0f, acc2 = 0.0f;
    #pragma unroll
    for (int i = 0; i < UPR; ++i) {
        const int gy = h * UPR + i;
        const float t = (float)gy / (float)(Hg - 1);
        const float r = expf(start + dr * t);
        const float gxn = r * sn + l0;
        const float gyn = r * cs + l1;
        const float ix = ((gxn + 1.0f) * (float)IMG - 1.0f) * 0.5f;
        const float iy = ((gyn + 1.0f) * (float)IMG - 1.0f) * 0.5f;
        const float x0f = floorf(ix);
        const float y0f = floorf(iy);
        const float wx = ix - x0f;
        const float wy = iy - y0f;
        int x0 = (int)x0f, y0 = (int)y0f;
        int x1 = x0 + 1,   y1 = y0 + 1;
        x0 = min(max(x0, 0), IMG - 1);
        x1 = min(max(x1, 0), IMG - 1);
        y0 = min(max(y0, 0), IMG - 1);
        y1 = min(max(y1, 0), IMG - 1);
        const float w00 = (1.0f - wx) * (1.0f - wy);
        const float w01 = wx * (1.0f - wy);
        const float w10 = (1.0f - wx) * wy;
        const float w11 = wx * wy;
        const int o00 = y0 * IMG + x0;
        const int o01 = y0 * IMG + x1;
        const int o10 = y1 * IMG + x0;
        const int o11 = y1 * IMG + x1;
        {
            const float* xc = xb;
            acc0 += xc[o00]*w00 + xc[o01]*w01 + xc[o10]*w10 + xc[o11]*w11;
        }
        {
            const float* xc = xb + IMG * IMG;
            acc1 += xc[o00]*w00 + xc[o01]*w01 + xc[o10]*w10 + xc[o11]*w11;
        }
        {
            const float* xc = xb + 2 * IMG * IMG;
            acc2 += xc[o00]*w00 + xc[o01]*w01 + xc[o10]*w10 + xc[o11]*w11;
        }
    }
    part[0 * Wg + tid] = acc0;
    part[1 * Wg + tid] = acc1;
    part[2 * Wg + tid] = acc2;
    __syncthreads();

    if (tid < Cn * Ww) {
        const int c = tid / Ww;
        const int w = tid % Ww;
        const float* p = part + c * Wg + w * UPT;
        float s = 0.0f;
        #pragma unroll
        for (int j = 0; j < UPT; ++j) s += p[j];
        out[(((size_t)b * Cn + c) * Hh + h) * Ww + w] = s * (1.0f / (UPR * UPT));
    }
}

// -------------------------------------------------------------------------
extern "C" void kernel_launch(void* const* d_in, const int* in_sizes, int n_in,
                              void* d_out, int out_size, void* d_ws, size_t ws_size,
                              hipStream_t stream) {
    const float* x       = (const float*)d_in[0];
    const float* ltp     = (const float*)d_in[1];
    const float* conv1_w = (const float*)d_in[2];
    const float* conv1_b = (const float*)d_in[3];
    const float* conv2_w = (const float*)d_in[4];
    const float* conv2_b = (const float*)d_in[5];
    const float* fc1_w   = (const float*)d_in[6];
    const float* fc1_b   = (const float*)d_in[7];
    const float* fc2_w   = (const float*)d_in[8];
    const float* fc2_b   = (const float*)d_in[9];
    float* out = (float*)d_out;

    // workspace: wsum (B*6*25) | wt (B*2)  — atomically accumulated, zero first
    float* wsum  = (float*)d_ws;
    float* wt_ws = wsum + Bn * C1 * 25;
    hipMemsetAsync(d_ws, 0, (size_t)(Bn * C1 * 25 + Bn * 2) * sizeof(float), stream);

    k1_fused<<<dim3((P1 + RPB - 1) / RPB, Bn), dim3(256), 0, stream>>>(x, conv1_w, conv1_b, wsum);
    k2_head<<<dim3(Bn), dim3(64), 0, stream>>>(wsum, conv2_w, conv2_b,
                                               fc1_w, fc1_b, fc2_w, fc2_b,
                                               wt_ws, out);
    k3_sample_pool<<<dim3(Hh, Bn), dim3(Wg), 0, stream>>>(x, ltp, wt_ws, out);
}

// Round 3
// 263.921 us; speedup vs baseline: 2.0800x; 1.4331x over previous
//
#include <hip/hip_runtime.h>
#include <hip/hip_bf16.h>
#include <math.h>

// Problem constants
#define Bn    64
#define Cn    3
#define IMG   224
#define PLANE (IMG*IMG)      // 50176
#define C1    6
#define P1    110            // conv1(220) + maxpool2 -> 110
#define P2    106            // conv2 output spatial
#define NVALID (P2*P2)       // 11236
#define Hh    32
#define Ww    64
#define UPR   10
#define UPT   10
#define Hg    (Hh*UPR)       // 320
#define Wg    (Ww*UPT)       // 640
#define POOLED_SIZE (Bn*Cn*Hh*Ww)   // 393216
#define RPB   4

// workspace layout
#define NHWC_FLOATS ((size_t)Bn * PLANE * 4)            // 12,845,056 floats
#define WS_NEEDED   (NHWC_FLOATS * 4 + (Bn*C1*25 + Bn*2) * 4)

// -------------------------------------------------------------------------
// K0: repack x (B,3,224,224) -> NHWC4 (B,224,224,4), c3 = 0.
// -------------------------------------------------------------------------
__global__ __launch_bounds__(256) void k0_repack(
    const float* __restrict__ x, float* __restrict__ x4)
{
    const int idx = blockIdx.x * 256 + threadIdx.x;    // 0 .. 64*50176-1
    const int b = idx / PLANE;
    const int p = idx - b * PLANE;
    const float* xb = x + (size_t)b * (Cn * PLANE);
    float4 v;
    v.x = xb[p];
    v.y = xb[p + PLANE];
    v.z = xb[p + 2 * PLANE];
    v.w = 0.0f;
    *(float4*)(x4 + ((size_t)b * PLANE + p) * 4) = v;
}

// -------------------------------------------------------------------------
// K1: fused conv1 (all 6 OCs) + maxpool2 + row window sums + atomic
// accumulate into the 25 conv2-window box-sums. Weights read via
// wave-uniform global loads (scalar cache) — keeps the LDS pipe free
// for the win ds_read_b128s.
// -------------------------------------------------------------------------
__global__ __launch_bounds__(256) void k1_fused(
    const float* __restrict__ x,      // (B,3,224,224)
    const float* __restrict__ w1,     // (6,3,5,5)
    const float* __restrict__ b1,     // (6,)
    float* __restrict__ wsum)         // (B,6,25) pre-zeroed
{
    __shared__ __attribute__((aligned(16))) float xs[3][12][224];  // 32256 B
    __shared__ float rowbuf[RPB][C1][112];                         // 10752 B

    const int b    = blockIdx.y;
    const int y0   = blockIdx.x * RPB;
    const int tid  = threadIdx.x;
    const int wid  = tid >> 6;
    const int lane = tid & 63;

    const float* xb = x + (size_t)b * (Cn * PLANE);
    const int gybase = 2 * y0;

    for (int i = tid; i < 3 * 12 * 56; i += 256) {
        const int ic  = i / (12 * 56);
        const int rem = i % (12 * 56);
        const int r   = rem / 56;
        const int c4  = rem % 56;
        const int gy  = gybase + r;
        if (gy < IMG) {
            const float4 v = *(const float4*)(xb + ic * PLANE + gy * IMG + c4 * 4);
            *(float4*)(&xs[ic][r][c4 * 4]) = v;
        }
    }
    __syncthreads();

    const int y = y0 + wid;
    const bool active = (lane < 55) && (y < P1);

    if (active) {
        float acc[C1][8];
        #pragma unroll
        for (int oc = 0; oc < C1; ++oc) {
            const float bv = b1[oc];                 // uniform -> s_load
            #pragma unroll
            for (int j = 0; j < 8; ++j) acc[oc][j] = bv;
        }

        #pragma unroll
        for (int ic = 0; ic < 3; ++ic) {
            float win[6][8];
            #pragma unroll
            for (int r = 0; r < 6; ++r) {
                const float4 a = *(const float4*)&xs[ic][2 * wid + r][4 * lane];
                const float4 c = *(const float4*)&xs[ic][2 * wid + r][4 * lane + 4];
                win[r][0] = a.x; win[r][1] = a.y; win[r][2] = a.z; win[r][3] = a.w;
                win[r][4] = c.x; win[r][5] = c.y; win[r][6] = c.z; win[r][7] = c.w;
            }
            #pragma unroll
            for (int oc = 0; oc < C1; ++oc) {
                const float* wp = w1 + (oc * 3 + ic) * 25;   // uniform -> s_load
                #pragma unroll
                for (int ky = 0; ky < 5; ++ky) {
                    #pragma unroll
                    for (int kx = 0; kx < 5; ++kx) {
                        const float wv = wp[ky * 5 + kx];
                        acc[oc][0] += win[ky    ][kx    ] * wv;
                        acc[oc][1] += win[ky    ][kx + 1] * wv;
                        acc[oc][2] += win[ky    ][kx + 2] * wv;
                        acc[oc][3] += win[ky    ][kx + 3] * wv;
                        acc[oc][4] += win[ky + 1][kx    ] * wv;
                        acc[oc][5] += win[ky + 1][kx + 1] * wv;
                        acc[oc][6] += win[ky + 1][kx + 2] * wv;
                        acc[oc][7] += win[ky + 1][kx + 3] * wv;
                    }
                }
            }
        }

        #pragma unroll
        for (int oc = 0; oc < C1; ++oc) {
            const float p0 = fmaxf(fmaxf(acc[oc][0], acc[oc][1]),
                                   fmaxf(acc[oc][4], acc[oc][5]));
            const float p1 = fmaxf(fmaxf(acc[oc][2], acc[oc][3]),
                                   fmaxf(acc[oc][6], acc[oc][7]));
            rowbuf[wid][oc][2 * lane]     = p0;
            rowbuf[wid][oc][2 * lane + 1] = p1;
        }
    }
    __syncthreads();

    if (lane < 30 && y < P1) {
        const int oc = lane / 5;
        const int kx = lane % 5;
        const float* rp = rowbuf[wid][oc];
        float s = 0.0f;
        for (int xq = kx; xq < kx + P2; ++xq) s += rp[xq];
        const int kylo = (y - 105 > 0) ? (y - 105) : 0;
        const int kyhi = (y < 4) ? y : 4;
        float* wp = wsum + ((size_t)b * C1 + oc) * 25 + kx;
        for (int ky = kylo; ky <= kyhi; ++ky)
            atomicAdd(wp + ky * 5, s);
    }
}

// -------------------------------------------------------------------------
// K2: head
// -------------------------------------------------------------------------
__global__ __launch_bounds__(64) void k2_head(
    const float* __restrict__ wsum, const float* __restrict__ w2,
    const float* __restrict__ b2, const float* __restrict__ fc1w,
    const float* __restrict__ fc1b, const float* __restrict__ fc2w,
    const float* __restrict__ fc2b, float* __restrict__ wt_ws,
    float* __restrict__ out)
{
    const int b = blockIdx.x;
    const int tid = threadIdx.x;
    __shared__ float sfeat[16];
    __shared__ float sh[8];

    const float* wsb = wsum + b * 150;
    if (tid < 16) {
        float s = 0.0f;
        for (int j = 0; j < 150; ++j) s += w2[tid * 150 + j] * wsb[j];
        sfeat[tid] = b2[tid] + s * (1.0f / (float)NVALID);
    }
    __syncthreads();
    if (tid < 8) {
        float s = fc1b[tid];
        #pragma unroll
        for (int j = 0; j < 16; ++j) s += fc1w[tid * 16 + j] * sfeat[j];
        sh[tid] = fmaxf(s, 0.0f);
    }
    __syncthreads();
    if (tid < 2) {
        float s = fc2b[tid];
        #pragma unroll
        for (int j = 0; j < 8; ++j) s += fc2w[tid * 8 + j] * sh[j];
        float sig = (s >= 0.0f) ? (1.0f / (1.0f + expf(-s)))
                                : (expf(s) / (1.0f + expf(s)));
        const float wgt = 5.0f * sig;
        wt_ws[b * 2 + tid] = wgt;
        out[POOLED_SIZE + b * 2 + tid] = wgt;
    }
}

// -------------------------------------------------------------------------
// Shared sampling math: clamp-coordinate formulation (verified equivalent
// to corner-clamp border mode at all boundary cases).
// -------------------------------------------------------------------------
__device__ __forceinline__ void sample_coords(
    float gxn, float gyn, int& x0, int& y0, float& wx, float& wy)
{
    float ix = ((gxn + 1.0f) * (float)IMG - 1.0f) * 0.5f;
    float iy = ((gyn + 1.0f) * (float)IMG - 1.0f) * 0.5f;
    ix = fminf(fmaxf(ix, 0.0f), (float)(IMG - 1));
    iy = fminf(fmaxf(iy, 0.0f), (float)(IMG - 1));
    x0 = (int)ix; if (x0 > IMG - 2) x0 = IMG - 2;
    y0 = (int)iy; if (y0 > IMG - 2) y0 = IMG - 2;
    wx = ix - (float)x0;
    wy = iy - (float)y0;
}

// -------------------------------------------------------------------------
// K3 (NHWC4): log-polar grid sample + 10x10 avg pool. One block per (b,h),
// 640 threads = one per gx. 4 aligned dwordx4 loads per sample.
// -------------------------------------------------------------------------
__global__ __launch_bounds__(640) void k3_sample_pool_nhwc(
    const float* __restrict__ x4,     // (B,224,224,4)
    const float* __restrict__ ltp,
    const float* __restrict__ wt,
    float* __restrict__ out)
{
    __shared__ float part[3 * Wg];

    const int h = blockIdx.x;
    const int b = blockIdx.y;
    const int tid = threadIdx.x;

    const float w0 = wt[b * 2 + 0];
    const float w1 = wt[b * 2 + 1];
    const float l0 = ltp[b * 2 + 0];
    const float l1 = ltp[b * 2 + 1];
    const float start = logf(0.01f * w0);
    const float stop  = logf(0.6f  * w1);
    const float dr = stop - start;

    const float angle = 6.283185307179586f * (float)tid / (float)Wg;
    const float sn = sinf(angle);
    const float cs = cosf(angle);

    const float* xb4 = x4 + (size_t)b * PLANE * 4;

    // radii via multiplicative recurrence: 2 exps instead of 10
    const float ratio = expf(dr * (1.0f / (float)(Hg - 1)));
    float r = expf(start + dr * ((float)(h * UPR) / (float)(Hg - 1)));

    float acc0 = 0.0f, acc1 = 0.0f, acc2 = 0.0f;
    #pragma unroll
    for (int i = 0; i < UPR; ++i) {
        int x0, y0; float wx, wy;
        sample_coords(r * sn + l0, r * cs + l1, x0, y0, wx, wy);
        r *= ratio;

        const float* base = xb4 + ((size_t)(y0 * IMG + x0)) * 4;
        const float4 a00 = *(const float4*)(base);
        const float4 a01 = *(const float4*)(base + 4);
        const float4 a10 = *(const float4*)(base + IMG * 4);
        const float4 a11 = *(const float4*)(base + IMG * 4 + 4);

        const float wx0 = 1.0f - wx, wy0 = 1.0f - wy;
        const float w00 = wx0 * wy0, w01 = wx * wy0;
        const float w10 = wx0 * wy,  w11 = wx * wy;

        acc0 += w00 * a00.x + w01 * a01.x + w10 * a10.x + w11 * a11.x;
        acc1 += w00 * a00.y + w01 * a01.y + w10 * a10.y + w11 * a11.y;
        acc2 += w00 * a00.z + w01 * a01.z + w10 * a10.z + w11 * a11.z;
    }
    part[0 * Wg + tid] = acc0;
    part[1 * Wg + tid] = acc1;
    part[2 * Wg + tid] = acc2;
    __syncthreads();

    if (tid < Cn * Ww) {
        const int c = tid / Ww;
        const int w = tid % Ww;
        const float* p = part + c * Wg + w * UPT;
        float s = 0.0f;
        #pragma unroll
        for (int j = 0; j < UPT; ++j) s += p[j];
        out[(((size_t)b * Cn + c) * Hh + h) * Ww + w] = s * (1.0f / (UPR * UPT));
    }
}

// -------------------------------------------------------------------------
// K3 fallback (NCHW scalar gathers) — only if ws_size can't hold NHWC4.
// -------------------------------------------------------------------------
__global__ __launch_bounds__(640) void k3_sample_pool_nchw(
    const float* __restrict__ x, const float* __restrict__ ltp,
    const float* __restrict__ wt, float* __restrict__ out)
{
    __shared__ float part[3 * Wg];
    const int h = blockIdx.x;
    const int b = blockIdx.y;
    const int tid = threadIdx.x;

    const float w0 = wt[b * 2 + 0];
    const float w1 = wt[b * 2 + 1];
    const float l0 = ltp[b * 2 + 0];
    const float l1 = ltp[b * 2 + 1];
    const float start = logf(0.01f * w0);
    const float stop  = logf(0.6f  * w1);
    const float dr = stop - start;
    const float angle = 6.283185307179586f * (float)tid / (float)Wg;
    const float sn = sinf(angle);
    const float cs = cosf(angle);
    const float* xb = x + (size_t)b * Cn * PLANE;

    const float ratio = expf(dr * (1.0f / (float)(Hg - 1)));
    float r = expf(start + dr * ((float)(h * UPR) / (float)(Hg - 1)));

    float acc0 = 0.0f, acc1 = 0.0f, acc2 = 0.0f;
    #pragma unroll
    for (int i = 0; i < UPR; ++i) {
        int x0, y0; float wx, wy;
        sample_coords(r * sn + l0, r * cs + l1, x0, y0, wx, wy);
        r *= ratio;
        const float wx0 = 1.0f - wx, wy0 = 1.0f - wy;
        const float w00 = wx0 * wy0, w01 = wx * wy0;
        const float w10 = wx0 * wy,  w11 = wx * wy;
        const int o00 = y0 * IMG + x0;
        #pragma unroll
        for (int c = 0; c < 3; ++c) {
            const float* xc = xb + c * PLANE;
            const float v = w00 * xc[o00] + w01 * xc[o00 + 1]
                          + w10 * xc[o00 + IMG] + w11 * xc[o00 + IMG + 1];
            if (c == 0) acc0 += v; else if (c == 1) acc1 += v; else acc2 += v;
        }
    }
    part[0 * Wg + tid] = acc0;
    part[1 * Wg + tid] = acc1;
    part[2 * Wg + tid] = acc2;
    __syncthreads();

    if (tid < Cn * Ww) {
        const int c = tid / Ww;
        const int w = tid % Ww;
        const float* p = part + c * Wg + w * UPT;
        float s = 0.0f;
        #pragma unroll
        for (int j = 0; j < UPT; ++j) s += p[j];
        out[(((size_t)b * Cn + c) * Hh + h) * Ww + w] = s * (1.0f / (UPR * UPT));
    }
}

// -------------------------------------------------------------------------
extern "C" void kernel_launch(void* const* d_in, const int* in_sizes, int n_in,
                              void* d_out, int out_size, void* d_ws, size_t ws_size,
                              hipStream_t stream) {
    const float* x       = (const float*)d_in[0];
    const float* ltp     = (const float*)d_in[1];
    const float* conv1_w = (const float*)d_in[2];
    const float* conv1_b = (const float*)d_in[3];
    const float* conv2_w = (const float*)d_in[4];
    const float* conv2_b = (const float*)d_in[5];
    const float* fc1_w   = (const float*)d_in[6];
    const float* fc1_b   = (const float*)d_in[7];
    const float* fc2_w   = (const float*)d_in[8];
    const float* fc2_b   = (const float*)d_in[9];
    float* out = (float*)d_out;

    const bool use_nhwc = (ws_size >= WS_NEEDED);

    float* x4    = (float*)d_ws;                      // 51.4 MB (if used)
    float* wsum  = use_nhwc ? (x4 + NHWC_FLOATS) : (float*)d_ws;
    float* wt_ws = wsum + Bn * C1 * 25;

    hipMemsetAsync(wsum, 0, (size_t)(Bn * C1 * 25 + Bn * 2) * sizeof(float), stream);

    if (use_nhwc)
        k0_repack<<<dim3(Bn * PLANE / 256), dim3(256), 0, stream>>>(x, x4);

    k1_fused<<<dim3((P1 + RPB - 1) / RPB, Bn), dim3(256), 0, stream>>>(x, conv1_w, conv1_b, wsum);
    k2_head<<<dim3(Bn), dim3(64), 0, stream>>>(wsum, conv2_w, conv2_b,
                                               fc1_w, fc1_b, fc2_w, fc2_b,
                                               wt_ws, out);
    if (use_nhwc)
        k3_sample_pool_nhwc<<<dim3(Hh, Bn), dim3(Wg), 0, stream>>>(x4, ltp, wt_ws, out);
    else
        k3_sample_pool_nchw<<<dim3(Hh, Bn), dim3(Wg), 0, stream>>>(x, ltp, wt_ws, out);
}

// Round 4
// 219.873 us; speedup vs baseline: 2.4967x; 1.2003x over previous
//
#include <hip/hip_runtime.h>
#include <math.h>

// Problem constants
#define Bn    64
#define Cn    3
#define IMG   224
#define PLANE (IMG*IMG)      // 50176
#define C1    6
#define P1    110            // conv1(220) + maxpool2 -> 110
#define P2    106            // conv2 output spatial
#define NVALID (P2*P2)       // 11236
#define Hh    32
#define Ww    64
#define UPR   10
#define UPT   10
#define Hg    (Hh*UPR)       // 320
#define Wg    (Ww*UPT)       // 640
#define POOLED_SIZE (Bn*Cn*Hh*Ww)   // 393216
#define RPB   4

typedef unsigned short u16;

// workspace: wsum (B*6*25 f32) | wt (B*2 f32) | x4b (B*224*224*4 bf16)
#define WSUM_FLOATS (Bn*C1*25 + Bn*2)
#define X4B_U16     ((size_t)Bn * PLANE * 4)
#define WS_NEEDED   ((size_t)WSUM_FLOATS * 4 + X4B_U16 * 2)

__device__ __forceinline__ u16 f2bf(float f) {
    union { unsigned int u; float f; } c; c.f = f;
    unsigned int r = c.u + 0x7fffu + ((c.u >> 16) & 1u);   // RNE
    return (u16)(r >> 16);
}
__device__ __forceinline__ float bf2f(u16 v) {
    union { unsigned int u; float f; } c; c.u = ((unsigned int)v) << 16;
    return c.f;
}

// -------------------------------------------------------------------------
// K1: fused conv1 (all 6 OCs) + maxpool2 + bf16-NHWC4 repack + shuffle-based
// window sums + atomic accumulate into the 25 conv2-window box-sums.
// Block = 256 threads = 4 waves; wave wid handles pooled row y0+wid.
// Lane l (<55) computes pooled cols (2l, 2l+1) for all 6 OCs via a rolling
// 2-row register window (keeps live regs ~80, no LDS re-reads).
// -------------------------------------------------------------------------
__global__ __launch_bounds__(256) void k1_fused(
    const float* __restrict__ x,      // (B,3,224,224)
    const float* __restrict__ w1,     // (6,3,5,5)
    const float* __restrict__ b1,     // (6,)
    float* __restrict__ wsum,         // (B,6,25) pre-zeroed
    u16* __restrict__ x4b,            // (B,224,224,4) bf16 out
    int do_pack)
{
    __shared__ __attribute__((aligned(16))) float xs[3][12][224];  // 32256 B

    const int b    = blockIdx.y;
    const int y0   = blockIdx.x * RPB;
    const int tid  = threadIdx.x;
    const int wid  = tid >> 6;
    const int lane = tid & 63;

    const float* xb = x + (size_t)b * (Cn * PLANE);
    const int gybase = 2 * y0;

    // stage 12 input rows x 3 ic, coalesced float4
    for (int i = tid; i < 3 * 12 * 56; i += 256) {
        const int ic  = i / (12 * 56);
        const int rem = i % (12 * 56);
        const int r   = rem / 56;
        const int c4  = rem % 56;
        const int gy  = gybase + r;
        if (gy < IMG)
            *(float4*)(&xs[ic][r][c4 * 4]) =
                *(const float4*)(xb + ic * PLANE + gy * IMG + c4 * 4);
    }
    __syncthreads();

    // bf16 NHWC4 pack of this block's 8 owned rows (28 blocks x 8 = 224)
    if (do_pack) {
        u16* ob = x4b + (size_t)b * PLANE * 4;
        for (int i = tid; i < 8 * IMG; i += 256) {
            const int r   = i / IMG;
            const int col = i % IMG;
            const int gy  = gybase + r;
            ushort4 v;
            v.x = f2bf(xs[0][r][col]);
            v.y = f2bf(xs[1][r][col]);
            v.z = f2bf(xs[2][r][col]);
            v.w = 0;
            *(ushort4*)(ob + ((size_t)gy * IMG + col) * 4) = v;
        }
    }

    const int y = y0 + wid;
    const bool rowvalid = (y < P1);
    const bool active = (lane < 55) && rowvalid;

    float pp0[C1], pp1[C1];
    if (active) {
        float acc[C1][8];
        #pragma unroll
        for (int oc = 0; oc < C1; ++oc) {
            const float bv = b1[oc];
            #pragma unroll
            for (int j = 0; j < 8; ++j) acc[oc][j] = bv;
        }

        #pragma unroll
        for (int ic = 0; ic < 3; ++ic) {
            float rTop[8], rBot[8];
            {
                const float* rp = &xs[ic][2 * wid][4 * lane];
                const float4 a = *(const float4*)rp;
                const float4 c = *(const float4*)(rp + 4);
                rTop[0]=a.x; rTop[1]=a.y; rTop[2]=a.z; rTop[3]=a.w;
                rTop[4]=c.x; rTop[5]=c.y; rTop[6]=c.z; rTop[7]=c.w;
            }
            {
                const float* rp = &xs[ic][2 * wid + 1][4 * lane];
                const float4 a = *(const float4*)rp;
                const float4 c = *(const float4*)(rp + 4);
                rBot[0]=a.x; rBot[1]=a.y; rBot[2]=a.z; rBot[3]=a.w;
                rBot[4]=c.x; rBot[5]=c.y; rBot[6]=c.z; rBot[7]=c.w;
            }
            #pragma unroll
            for (int ky = 0; ky < 5; ++ky) {
                #pragma unroll
                for (int oc = 0; oc < C1; ++oc) {
                    const float* wrow = w1 + ((oc * 3 + ic) * 25 + ky * 5);
                    #pragma unroll
                    for (int kx = 0; kx < 5; ++kx) {
                        const float wv = wrow[kx];       // wave-uniform s_load
                        acc[oc][0] += rTop[kx    ] * wv;
                        acc[oc][1] += rTop[kx + 1] * wv;
                        acc[oc][2] += rTop[kx + 2] * wv;
                        acc[oc][3] += rTop[kx + 3] * wv;
                        acc[oc][4] += rBot[kx    ] * wv;
                        acc[oc][5] += rBot[kx + 1] * wv;
                        acc[oc][6] += rBot[kx + 2] * wv;
                        acc[oc][7] += rBot[kx + 3] * wv;
                    }
                }
                if (ky < 4) {
                    #pragma unroll
                    for (int j = 0; j < 8; ++j) rTop[j] = rBot[j];
                    const float* rp = &xs[ic][2 * wid + ky + 2][4 * lane];
                    const float4 a = *(const float4*)rp;
                    const float4 c = *(const float4*)(rp + 4);
                    rBot[0]=a.x; rBot[1]=a.y; rBot[2]=a.z; rBot[3]=a.w;
                    rBot[4]=c.x; rBot[5]=c.y; rBot[6]=c.z; rBot[7]=c.w;
                }
            }
        }

        #pragma unroll
        for (int oc = 0; oc < C1; ++oc) {
            pp0[oc] = fmaxf(fmaxf(acc[oc][0], acc[oc][1]),
                            fmaxf(acc[oc][4], acc[oc][5]));
            pp1[oc] = fmaxf(fmaxf(acc[oc][2], acc[oc][3]),
                            fmaxf(acc[oc][6], acc[oc][7]));
        }
    } else {
        #pragma unroll
        for (int oc = 0; oc < C1; ++oc) { pp0[oc] = 0.0f; pp1[oc] = 0.0f; }
    }

    // Wave-level windowed row sums + atomic scatter (no LDS, no 2nd barrier).
    // Row window [kx, kx+105]: win[kx] = full - prefix(kx) - suffix(4-kx).
    #pragma unroll
    for (int oc = 0; oc < C1; ++oc) {
        float s = pp0[oc] + pp1[oc];
        #pragma unroll
        for (int off = 32; off > 0; off >>= 1) s += __shfl_xor(s, off, 64);
        const float c0   = __shfl(pp0[oc], 0, 64);
        const float c1   = __shfl(pp1[oc], 0, 64);
        const float c2   = __shfl(pp0[oc], 1, 64);
        const float c3   = __shfl(pp1[oc], 1, 64);
        const float c106 = __shfl(pp0[oc], 53, 64);
        const float c107 = __shfl(pp1[oc], 53, 64);
        const float c108 = __shfl(pp0[oc], 54, 64);
        const float c109 = __shfl(pp1[oc], 54, 64);
        const float w0v = s - (c106 + c107 + c108 + c109);
        const float w1v = s - c0 - (c107 + c108 + c109);
        const float w2v = s - (c0 + c1) - (c108 + c109);
        const float w3v = s - (c0 + c1 + c2) - c109;
        const float w4v = s - (c0 + c1 + c2 + c3);
        if (rowvalid && lane < 25) {
            const int ky = lane / 5;
            const int kx = lane % 5;
            if ((unsigned)(y - ky) <= 105u) {   // ky <= y && y-ky <= 105
                float wv = w0v;
                wv = (kx == 1) ? w1v : wv;
                wv = (kx == 2) ? w2v : wv;
                wv = (kx == 3) ? w3v : wv;
                wv = (kx == 4) ? w4v : wv;
                atomicAdd(wsum + ((size_t)b * C1 + oc) * 25 + lane, wv);
            }
        }
    }
}

// -------------------------------------------------------------------------
// K2: head — feat = b2 + (W2 . wsum)/11236 ; fc1+relu ; fc2+sigmoid*5.
// -------------------------------------------------------------------------
__global__ __launch_bounds__(64) void k2_head(
    const float* __restrict__ wsum, const float* __restrict__ w2,
    const float* __restrict__ b2, const float* __restrict__ fc1w,
    const float* __restrict__ fc1b, const float* __restrict__ fc2w,
    const float* __restrict__ fc2b, float* __restrict__ wt_ws,
    float* __restrict__ out)
{
    const int b = blockIdx.x;
    const int tid = threadIdx.x;
    __shared__ float sfeat[16];
    __shared__ float sh[8];

    const float* wsb = wsum + b * 150;
    if (tid < 16) {
        float s = 0.0f;
        for (int j = 0; j < 150; ++j) s += w2[tid * 150 + j] * wsb[j];
        sfeat[tid] = b2[tid] + s * (1.0f / (float)NVALID);
    }
    __syncthreads();
    if (tid < 8) {
        float s = fc1b[tid];
        #pragma unroll
        for (int j = 0; j < 16; ++j) s += fc1w[tid * 16 + j] * sfeat[j];
        sh[tid] = fmaxf(s, 0.0f);
    }
    __syncthreads();
    if (tid < 2) {
        float s = fc2b[tid];
        #pragma unroll
        for (int j = 0; j < 8; ++j) s += fc2w[tid * 8 + j] * sh[j];
        float sig = (s >= 0.0f) ? (1.0f / (1.0f + expf(-s)))
                                : (expf(s) / (1.0f + expf(s)));
        const float wgt = 5.0f * sig;
        wt_ws[b * 2 + tid] = wgt;
        out[POOLED_SIZE + b * 2 + tid] = wgt;
    }
}

// -------------------------------------------------------------------------
// Clamp-coordinate sampling (equivalent to corner-clamp border mode).
// -------------------------------------------------------------------------
__device__ __forceinline__ void sample_coords(
    float gxn, float gyn, int& x0, int& y0, float& wx, float& wy)
{
    float ix = ((gxn + 1.0f) * (float)IMG - 1.0f) * 0.5f;
    float iy = ((gyn + 1.0f) * (float)IMG - 1.0f) * 0.5f;
    ix = fminf(fmaxf(ix, 0.0f), (float)(IMG - 1));
    iy = fminf(fmaxf(iy, 0.0f), (float)(IMG - 1));
    x0 = (int)ix; if (x0 > IMG - 2) x0 = IMG - 2;
    y0 = (int)iy; if (y0 > IMG - 2) y0 = IMG - 2;
    wx = ix - (float)x0;
    wy = iy - (float)y0;
}

// -------------------------------------------------------------------------
// K3 (bf16 NHWC4): log-polar grid sample + 10x10 avg pool.
// One block per (b,h), 640 threads = one per gx. 4 x 8B loads per sample.
// -------------------------------------------------------------------------
__global__ __launch_bounds__(640) void k3_sample_pool_bf16(
    const u16* __restrict__ x4b,      // (B,224,224,4) bf16
    const float* __restrict__ ltp,
    const float* __restrict__ wt,
    float* __restrict__ out)
{
    __shared__ float part[3 * Wg];

    const int h = blockIdx.x;
    const int b = blockIdx.y;
    const int tid = threadIdx.x;

    const float w0 = wt[b * 2 + 0];
    const float w1 = wt[b * 2 + 1];
    const float l0 = ltp[b * 2 + 0];
    const float l1 = ltp[b * 2 + 1];
    const float start = logf(0.01f * w0);
    const float stop  = logf(0.6f  * w1);
    const float dr = stop - start;

    const float angle = 6.283185307179586f * (float)tid / (float)Wg;
    const float sn = sinf(angle);
    const float cs = cosf(angle);

    const u16* xb4 = x4b + (size_t)b * PLANE * 4;

    const float ratio = expf(dr * (1.0f / (float)(Hg - 1)));
    float r = expf(start + dr * ((float)(h * UPR) / (float)(Hg - 1)));

    float acc0 = 0.0f, acc1 = 0.0f, acc2 = 0.0f;
    #pragma unroll
    for (int i = 0; i < UPR; ++i) {
        int x0, y0; float wx, wy;
        sample_coords(r * sn + l0, r * cs + l1, x0, y0, wx, wy);
        r *= ratio;

        const u16* base = xb4 + ((size_t)(y0 * IMG + x0)) * 4;
        const ushort4 a00 = *(const ushort4*)(base);
        const ushort4 a01 = *(const ushort4*)(base + 4);
        const ushort4 a10 = *(const ushort4*)(base + IMG * 4);
        const ushort4 a11 = *(const ushort4*)(base + IMG * 4 + 4);

        const float wx0 = 1.0f - wx, wy0 = 1.0f - wy;
        const float w00 = wx0 * wy0, w01 = wx * wy0;
        const float w10 = wx0 * wy,  w11 = wx * wy;

        acc0 += w00*bf2f(a00.x) + w01*bf2f(a01.x) + w10*bf2f(a10.x) + w11*bf2f(a11.x);
        acc1 += w00*bf2f(a00.y) + w01*bf2f(a01.y) + w10*bf2f(a10.y) + w11*bf2f(a11.y);
        acc2 += w00*bf2f(a00.z) + w01*bf2f(a01.z) + w10*bf2f(a10.z) + w11*bf2f(a11.z);
    }
    part[0 * Wg + tid] = acc0;
    part[1 * Wg + tid] = acc1;
    part[2 * Wg + tid] = acc2;
    __syncthreads();

    if (tid < Cn * Ww) {
        const int c = tid / Ww;
        const int w = tid % Ww;
        const float* p = part + c * Wg + w * UPT;
        float s = 0.0f;
        #pragma unroll
        for (int j = 0; j < UPT; ++j) s += p[j];
        out[(((size_t)b * Cn + c) * Hh + h) * Ww + w] = s * (1.0f / (UPR * UPT));
    }
}

// -------------------------------------------------------------------------
// K3 fallback (NCHW fp32 scalar gathers) — only if ws too small for x4b.
// -------------------------------------------------------------------------
__global__ __launch_bounds__(640) void k3_sample_pool_nchw(
    const float* __restrict__ x, const float* __restrict__ ltp,
    const float* __restrict__ wt, float* __restrict__ out)
{
    __shared__ float part[3 * Wg];
    const int h = blockIdx.x;
    const int b = blockIdx.y;
    const int tid = threadIdx.x;

    const float w0 = wt[b * 2 + 0];
    const float w1 = wt[b * 2 + 1];
    const float l0 = ltp[b * 2 + 0];
    const float l1 = ltp[b * 2 + 1];
    const float start = logf(0.01f * w0);
    const float stop  = logf(0.6f  * w1);
    const float dr = stop - start;
    const float angle = 6.283185307179586f * (float)tid / (float)Wg;
    const float sn = sinf(angle);
    const float cs = cosf(angle);
    const float* xb = x + (size_t)b * Cn * PLANE;

    const float ratio = expf(dr * (1.0f / (float)(Hg - 1)));
    float r = expf(start + dr * ((float)(h * UPR) / (float)(Hg - 1)));

    float acc0 = 0.0f, acc1 = 0.0f, acc2 = 0.0f;
    #pragma unroll
    for (int i = 0; i < UPR; ++i) {
        int x0, y0; float wx, wy;
        sample_coords(r * sn + l0, r * cs + l1, x0, y0, wx, wy);
        r *= ratio;
        const float wx0 = 1.0f - wx, wy0 = 1.0f - wy;
        const float w00 = wx0 * wy0, w01 = wx * wy0;
        const float w10 = wx0 * wy,  w11 = wx * wy;
        const int o00 = y0 * IMG + x0;
        acc0 += w00*xb[o00] + w01*xb[o00+1] + w10*xb[o00+IMG] + w11*xb[o00+IMG+1];
        const float* x1p = xb + PLANE;
        acc1 += w00*x1p[o00] + w01*x1p[o00+1] + w10*x1p[o00+IMG] + w11*x1p[o00+IMG+1];
        const float* x2p = xb + 2 * PLANE;
        acc2 += w00*x2p[o00] + w01*x2p[o00+1] + w10*x2p[o00+IMG] + w11*x2p[o00+IMG+1];
    }
    part[0 * Wg + tid] = acc0;
    part[1 * Wg + tid] = acc1;
    part[2 * Wg + tid] = acc2;
    __syncthreads();

    if (tid < Cn * Ww) {
        const int c = tid / Ww;
        const int w = tid % Ww;
        const float* p = part + c * Wg + w * UPT;
        float s = 0.0f;
        #pragma unroll
        for (int j = 0; j < UPT; ++j) s += p[j];
        out[(((size_t)b * Cn + c) * Hh + h) * Ww + w] = s * (1.0f / (UPR * UPT));
    }
}

// -------------------------------------------------------------------------
extern "C" void kernel_launch(void* const* d_in, const int* in_sizes, int n_in,
                              void* d_out, int out_size, void* d_ws, size_t ws_size,
                              hipStream_t stream) {
    const float* x       = (const float*)d_in[0];
    const float* ltp     = (const float*)d_in[1];
    const float* conv1_w = (const float*)d_in[2];
    const float* conv1_b = (const float*)d_in[3];
    const float* conv2_w = (const float*)d_in[4];
    const float* conv2_b = (const float*)d_in[5];
    const float* fc1_w   = (const float*)d_in[6];
    const float* fc1_b   = (const float*)d_in[7];
    const float* fc2_w   = (const float*)d_in[8];
    const float* fc2_b   = (const float*)d_in[9];
    float* out = (float*)d_out;

    const int do_pack = (ws_size >= WS_NEEDED) ? 1 : 0;

    float* wsum  = (float*)d_ws;                  // B*6*25
    float* wt_ws = wsum + Bn * C1 * 25;           // B*2
    u16*   x4b   = (u16*)(wt_ws + Bn * 2);        // 8B-aligned (38912 % 8 == 0)

    hipMemsetAsync(d_ws, 0, (size_t)WSUM_FLOATS * sizeof(float), stream);

    k1_fused<<<dim3((P1 + RPB - 1) / RPB, Bn), dim3(256), 0, stream>>>(
        x, conv1_w, conv1_b, wsum, x4b, do_pack);
    k2_head<<<dim3(Bn), dim3(64), 0, stream>>>(wsum, conv2_w, conv2_b,
                                               fc1_w, fc1_b, fc2_w, fc2_b,
                                               wt_ws, out);
    if (do_pack)
        k3_sample_pool_bf16<<<dim3(Hh, Bn), dim3(Wg), 0, stream>>>(x4b, ltp, wt_ws, out);
    else
        k3_sample_pool_nchw<<<dim3(Hh, Bn), dim3(Wg), 0, stream>>>(x, ltp, wt_ws, out);
}

// Round 5
// 200.644 us; speedup vs baseline: 2.7360x; 1.0958x over previous
//
#include <hip/hip_runtime.h>
#include <math.h>

// Problem constants
#define Bn    64
#define Cn    3
#define IMG   224
#define PLANE (IMG*IMG)      // 50176
#define C1    6
#define P1    110            // conv1(220) + maxpool2 -> 110
#define P2    106            // conv2 output spatial
#define NVALID (P2*P2)       // 11236
#define Hh    32
#define Ww    64
#define UPR   10
#define UPT   10
#define Hg    (Hh*UPR)       // 320
#define Wg    (Ww*UPT)       // 640
#define POOLED_SIZE (Bn*Cn*Hh*Ww)   // 393216
#define RPB   8              // pooled rows per block (1 per wave, 8 waves)
#define SROWS (2*RPB+2)      // 18 staged input rows

typedef unsigned short u16;

// workspace: wsum (B*6*25 f32) | wt (B*2 f32) | x4b (B*224*224*4 bf16)
#define WSUM_FLOATS (Bn*C1*25 + Bn*2)
#define X4B_U16     ((size_t)Bn * PLANE * 4)
#define WS_NEEDED   ((size_t)WSUM_FLOATS * 4 + X4B_U16 * 2)

__device__ __forceinline__ u16 f2bf(float f) {
    union { unsigned int u; float f; } c; c.f = f;
    unsigned int r = c.u + 0x7fffu + ((c.u >> 16) & 1u);   // RNE
    return (u16)(r >> 16);
}
__device__ __forceinline__ float bf2f(u16 v) {
    union { unsigned int u; float f; } c; c.u = ((unsigned int)v) << 16;
    return c.f;
}

// -------------------------------------------------------------------------
// K1: fused conv1 (all 6 OCs) + maxpool2 + bf16-NHWC4 repack + shuffle
// window sums + atomic accumulate into the 25 conv2-window box-sums.
// Block = 512 threads = 8 waves; wave wid handles pooled row y0+wid.
// Lane l (<55) computes pooled cols (2l, 2l+1) for all 6 OCs via a rolling
// 2-row register window.
// -------------------------------------------------------------------------
__global__ __launch_bounds__(512) void k1_fused(
    const float* __restrict__ x,      // (B,3,224,224)
    const float* __restrict__ w1,     // (6,3,5,5)
    const float* __restrict__ b1,     // (6,)
    float* __restrict__ wsum,         // (B,6,25) pre-zeroed
    u16* __restrict__ x4b,            // (B,224,224,4) bf16 out
    int do_pack)
{
    __shared__ __attribute__((aligned(16))) float xs[3][SROWS][224];  // 48384 B

    const int b    = blockIdx.y;
    const int y0   = blockIdx.x * RPB;
    const int tid  = threadIdx.x;
    const int wid  = tid >> 6;
    const int lane = tid & 63;

    const float* xb = x + (size_t)b * (Cn * PLANE);
    const int gybase = 2 * y0;

    // stage SROWS input rows x 3 ic, coalesced float4: 3*18*56 = 3024 vec4
    #pragma unroll
    for (int it = 0; it < 6; ++it) {
        const int i = tid + it * 512;
        if (i < 3 * SROWS * 56) {
            const int ic  = i / (SROWS * 56);
            const int rem = i - ic * (SROWS * 56);
            const int r   = rem / 56;
            const int c4  = rem - r * 56;
            const int gy  = gybase + r;
            if (gy < IMG)
                *(float4*)(&xs[ic][r][c4 * 4]) =
                    *(const float4*)(xb + ic * PLANE + gy * IMG + c4 * 4);
        }
    }
    __syncthreads();

    // bf16 NHWC4 pack of this block's 16 owned rows (14 blocks x 16 = 224)
    if (do_pack) {
        u16* ob = x4b + (size_t)b * PLANE * 4;
        #pragma unroll
        for (int it = 0; it < 7; ++it) {
            const int i   = tid + it * 512;       // < 16*224 = 3584
            const int r   = i / IMG;
            const int col = i - r * IMG;
            const int gy  = gybase + r;
            ushort4 v;
            v.x = f2bf(xs[0][r][col]);
            v.y = f2bf(xs[1][r][col]);
            v.z = f2bf(xs[2][r][col]);
            v.w = 0;
            *(ushort4*)(ob + ((size_t)gy * IMG + col) * 4) = v;
        }
    }

    const int y = y0 + wid;
    const bool rowvalid = (y < P1);
    const bool active = (lane < 55) && rowvalid;

    float pp0[C1], pp1[C1];
    if (active) {
        float acc[C1][8];
        #pragma unroll
        for (int oc = 0; oc < C1; ++oc) {
            const float bv = b1[oc];
            #pragma unroll
            for (int j = 0; j < 8; ++j) acc[oc][j] = bv;
        }

        #pragma unroll
        for (int ic = 0; ic < 3; ++ic) {
            float rTop[8], rBot[8];
            {
                const float* rp = &xs[ic][2 * wid][4 * lane];
                const float4 a = *(const float4*)rp;
                const float4 c = *(const float4*)(rp + 4);
                rTop[0]=a.x; rTop[1]=a.y; rTop[2]=a.z; rTop[3]=a.w;
                rTop[4]=c.x; rTop[5]=c.y; rTop[6]=c.z; rTop[7]=c.w;
            }
            {
                const float* rp = &xs[ic][2 * wid + 1][4 * lane];
                const float4 a = *(const float4*)rp;
                const float4 c = *(const float4*)(rp + 4);
                rBot[0]=a.x; rBot[1]=a.y; rBot[2]=a.z; rBot[3]=a.w;
                rBot[4]=c.x; rBot[5]=c.y; rBot[6]=c.z; rBot[7]=c.w;
            }
            #pragma unroll
            for (int ky = 0; ky < 5; ++ky) {
                #pragma unroll
                for (int oc = 0; oc < C1; ++oc) {
                    const float* wrow = w1 + ((oc * 3 + ic) * 25 + ky * 5);
                    #pragma unroll
                    for (int kx = 0; kx < 5; ++kx) {
                        const float wv = wrow[kx];       // wave-uniform s_load
                        acc[oc][0] += rTop[kx    ] * wv;
                        acc[oc][1] += rTop[kx + 1] * wv;
                        acc[oc][2] += rTop[kx + 2] * wv;
                        acc[oc][3] += rTop[kx + 3] * wv;
                        acc[oc][4] += rBot[kx    ] * wv;
                        acc[oc][5] += rBot[kx + 1] * wv;
                        acc[oc][6] += rBot[kx + 2] * wv;
                        acc[oc][7] += rBot[kx + 3] * wv;
                    }
                }
                if (ky < 4) {
                    #pragma unroll
                    for (int j = 0; j < 8; ++j) rTop[j] = rBot[j];
                    const float* rp = &xs[ic][2 * wid + ky + 2][4 * lane];
                    const float4 a = *(const float4*)rp;
                    const float4 c = *(const float4*)(rp + 4);
                    rBot[0]=a.x; rBot[1]=a.y; rBot[2]=a.z; rBot[3]=a.w;
                    rBot[4]=c.x; rBot[5]=c.y; rBot[6]=c.z; rBot[7]=c.w;
                }
            }
        }

        #pragma unroll
        for (int oc = 0; oc < C1; ++oc) {
            pp0[oc] = fmaxf(fmaxf(acc[oc][0], acc[oc][1]),
                            fmaxf(acc[oc][4], acc[oc][5]));
            pp1[oc] = fmaxf(fmaxf(acc[oc][2], acc[oc][3]),
                            fmaxf(acc[oc][6], acc[oc][7]));
        }
    } else {
        #pragma unroll
        for (int oc = 0; oc < C1; ++oc) { pp0[oc] = 0.0f; pp1[oc] = 0.0f; }
    }

    // Wave-level windowed row sums + atomic scatter.
    #pragma unroll
    for (int oc = 0; oc < C1; ++oc) {
        float s = pp0[oc] + pp1[oc];
        #pragma unroll
        for (int off = 32; off > 0; off >>= 1) s += __shfl_xor(s, off, 64);
        const float c0   = __shfl(pp0[oc], 0, 64);
        const float c1   = __shfl(pp1[oc], 0, 64);
        const float c2   = __shfl(pp0[oc], 1, 64);
        const float c3   = __shfl(pp1[oc], 1, 64);
        const float c106 = __shfl(pp0[oc], 53, 64);
        const float c107 = __shfl(pp1[oc], 53, 64);
        const float c108 = __shfl(pp0[oc], 54, 64);
        const float c109 = __shfl(pp1[oc], 54, 64);
        const float w0v = s - (c106 + c107 + c108 + c109);
        const float w1v = s - c0 - (c107 + c108 + c109);
        const float w2v = s - (c0 + c1) - (c108 + c109);
        const float w3v = s - (c0 + c1 + c2) - c109;
        const float w4v = s - (c0 + c1 + c2 + c3);
        if (rowvalid && lane < 25) {
            const int ky = lane / 5;
            const int kx = lane % 5;
            if ((unsigned)(y - ky) <= 105u) {
                float wv = w0v;
                wv = (kx == 1) ? w1v : wv;
                wv = (kx == 2) ? w2v : wv;
                wv = (kx == 3) ? w3v : wv;
                wv = (kx == 4) ? w4v : wv;
                atomicAdd(wsum + ((size_t)b * C1 + oc) * 25 + lane, wv);
            }
        }
    }
}

// -------------------------------------------------------------------------
// K2: head — feat = b2 + (W2 . wsum)/11236 ; fc1+relu ; fc2+sigmoid*5.
// -------------------------------------------------------------------------
__global__ __launch_bounds__(64) void k2_head(
    const float* __restrict__ wsum, const float* __restrict__ w2,
    const float* __restrict__ b2, const float* __restrict__ fc1w,
    const float* __restrict__ fc1b, const float* __restrict__ fc2w,
    const float* __restrict__ fc2b, float* __restrict__ wt_ws,
    float* __restrict__ out)
{
    const int b = blockIdx.x;
    const int tid = threadIdx.x;
    __shared__ float sfeat[16];
    __shared__ float sh[8];

    const float* wsb = wsum + b * 150;
    if (tid < 16) {
        float s = 0.0f;
        for (int j = 0; j < 150; ++j) s += w2[tid * 150 + j] * wsb[j];
        sfeat[tid] = b2[tid] + s * (1.0f / (float)NVALID);
    }
    __syncthreads();
    if (tid < 8) {
        float s = fc1b[tid];
        #pragma unroll
        for (int j = 0; j < 16; ++j) s += fc1w[tid * 16 + j] * sfeat[j];
        sh[tid] = fmaxf(s, 0.0f);
    }
    __syncthreads();
    if (tid < 2) {
        float s = fc2b[tid];
        #pragma unroll
        for (int j = 0; j < 8; ++j) s += fc2w[tid * 8 + j] * sh[j];
        float sig = (s >= 0.0f) ? (1.0f / (1.0f + expf(-s)))
                                : (expf(s) / (1.0f + expf(s)));
        const float wgt = 5.0f * sig;
        wt_ws[b * 2 + tid] = wgt;
        out[POOLED_SIZE + b * 2 + tid] = wgt;
    }
}

// -------------------------------------------------------------------------
// Clamp-coordinate sampling (equivalent to corner-clamp border mode).
// -------------------------------------------------------------------------
__device__ __forceinline__ void sample_coords(
    float gxn, float gyn, int& x0, int& y0, float& wx, float& wy)
{
    float ix = ((gxn + 1.0f) * (float)IMG - 1.0f) * 0.5f;
    float iy = ((gyn + 1.0f) * (float)IMG - 1.0f) * 0.5f;
    ix = fminf(fmaxf(ix, 0.0f), (float)(IMG - 1));
    iy = fminf(fmaxf(iy, 0.0f), (float)(IMG - 1));
    x0 = (int)ix; if (x0 > IMG - 2) x0 = IMG - 2;
    y0 = (int)iy; if (y0 > IMG - 2) y0 = IMG - 2;
    wx = ix - (float)x0;
    wy = iy - (float)y0;
}

// -------------------------------------------------------------------------
// K3 (bf16 NHWC4): log-polar grid sample + 10x10 avg pool.
// XCD-affinity swizzle: linear block L -> XCD L%8 (round-robin heuristic);
// we map b = (L&7) + 8*(L>>8) so one XCD serves 8 images (3.2 MB <= 4 MB L2)
// and walks each image's 32 h-blocks consecutively -> image stays L2-resident.
// -------------------------------------------------------------------------
__global__ __launch_bounds__(640) void k3_sample_pool_bf16(
    const u16* __restrict__ x4b,      // (B,224,224,4) bf16
    const float* __restrict__ ltp,
    const float* __restrict__ wt,
    float* __restrict__ out)
{
    __shared__ float part[3 * Wg];

    const int L = blockIdx.x;         // 0..2047
    const int q = L >> 3;             // 0..255
    const int h = q & 31;
    const int b = (L & 7) + 8 * (q >> 5);
    const int tid = threadIdx.x;

    const float w0 = wt[b * 2 + 0];
    const float w1 = wt[b * 2 + 1];
    const float l0 = ltp[b * 2 + 0];
    const float l1 = ltp[b * 2 + 1];
    const float start = logf(0.01f * w0);
    const float stop  = logf(0.6f  * w1);
    const float dr = stop - start;

    const float angle = 6.283185307179586f * (float)tid / (float)Wg;
    const float sn = sinf(angle);
    const float cs = cosf(angle);

    const u16* xb4 = x4b + (size_t)b * PLANE * 4;

    const float ratio = expf(dr * (1.0f / (float)(Hg - 1)));
    float r = expf(start + dr * ((float)(h * UPR) / (float)(Hg - 1)));

    float acc0 = 0.0f, acc1 = 0.0f, acc2 = 0.0f;
    #pragma unroll
    for (int i = 0; i < UPR; ++i) {
        int x0, y0; float wx, wy;
        sample_coords(r * sn + l0, r * cs + l1, x0, y0, wx, wy);
        r *= ratio;

        const u16* base = xb4 + ((size_t)(y0 * IMG + x0)) * 4;
        const ushort4 a00 = *(const ushort4*)(base);
        const ushort4 a01 = *(const ushort4*)(base + 4);
        const ushort4 a10 = *(const ushort4*)(base + IMG * 4);
        const ushort4 a11 = *(const ushort4*)(base + IMG * 4 + 4);

        const float wx0 = 1.0f - wx, wy0 = 1.0f - wy;
        const float w00 = wx0 * wy0, w01 = wx * wy0;
        const float w10 = wx0 * wy,  w11 = wx * wy;

        acc0 += w00*bf2f(a00.x) + w01*bf2f(a01.x) + w10*bf2f(a10.x) + w11*bf2f(a11.x);
        acc1 += w00*bf2f(a00.y) + w01*bf2f(a01.y) + w10*bf2f(a10.y) + w11*bf2f(a11.y);
        acc2 += w00*bf2f(a00.z) + w01*bf2f(a01.z) + w10*bf2f(a10.z) + w11*bf2f(a11.z);
    }
    part[0 * Wg + tid] = acc0;
    part[1 * Wg + tid] = acc1;
    part[2 * Wg + tid] = acc2;
    __syncthreads();

    if (tid < Cn * Ww) {
        const int c = tid / Ww;
        const int w = tid % Ww;
        const float* p = part + c * Wg + w * UPT;
        float s = 0.0f;
        #pragma unroll
        for (int j = 0; j < UPT; ++j) s += p[j];
        out[(((size_t)b * Cn + c) * Hh + h) * Ww + w] = s * (1.0f / (UPR * UPT));
    }
}

// -------------------------------------------------------------------------
// K3 fallback (NCHW fp32 scalar gathers) — only if ws too small for x4b.
// -------------------------------------------------------------------------
__global__ __launch_bounds__(640) void k3_sample_pool_nchw(
    const float* __restrict__ x, const float* __restrict__ ltp,
    const float* __restrict__ wt, float* __restrict__ out)
{
    __shared__ float part[3 * Wg];
    const int L = blockIdx.x;
    const int q = L >> 3;
    const int h = q & 31;
    const int b = (L & 7) + 8 * (q >> 5);
    const int tid = threadIdx.x;

    const float w0 = wt[b * 2 + 0];
    const float w1 = wt[b * 2 + 1];
    const float l0 = ltp[b * 2 + 0];
    const float l1 = ltp[b * 2 + 1];
    const float start = logf(0.01f * w0);
    const float stop  = logf(0.6f  * w1);
    const float dr = stop - start;
    const float angle = 6.283185307179586f * (float)tid / (float)Wg;
    const float sn = sinf(angle);
    const float cs = cosf(angle);
    const float* xb = x + (size_t)b * Cn * PLANE;

    const float ratio = expf(dr * (1.0f / (float)(Hg - 1)));
    float r = expf(start + dr * ((float)(h * UPR) / (float)(Hg - 1)));

    float acc0 = 0.0f, acc1 = 0.0f, acc2 = 0.0f;
    #pragma unroll
    for (int i = 0; i < UPR; ++i) {
        int x0, y0; float wx, wy;
        sample_coords(r * sn + l0, r * cs + l1, x0, y0, wx, wy);
        r *= ratio;
        const float wx0 = 1.0f - wx, wy0 = 1.0f - wy;
        const float w00 = wx0 * wy0, w01 = wx * wy0;
        const float w10 = wx0 * wy,  w11 = wx * wy;
        const int o00 = y0 * IMG + x0;
        acc0 += w00*xb[o00] + w01*xb[o00+1] + w10*xb[o00+IMG] + w11*xb[o00+IMG+1];
        const float* x1p = xb + PLANE;
        acc1 += w00*x1p[o00] + w01*x1p[o00+1] + w10*x1p[o00+IMG] + w11*x1p[o00+IMG+1];
        const float* x2p = xb + 2 * PLANE;
        acc2 += w00*x2p[o00] + w01*x2p[o00+1] + w10*x2p[o00+IMG] + w11*x2p[o00+IMG+1];
    }
    part[0 * Wg + tid] = acc0;
    part[1 * Wg + tid] = acc1;
    part[2 * Wg + tid] = acc2;
    __syncthreads();

    if (tid < Cn * Ww) {
        const int c = tid / Ww;
        const int w = tid % Ww;
        const float* p = part + c * Wg + w * UPT;
        float s = 0.0f;
        #pragma unroll
        for (int j = 0; j < UPT; ++j) s += p[j];
        out[(((size_t)b * Cn + c) * Hh + h) * Ww + w] = s * (1.0f / (UPR * UPT));
    }
}

// -------------------------------------------------------------------------
extern "C" void kernel_launch(void* const* d_in, const int* in_sizes, int n_in,
                              void* d_out, int out_size, void* d_ws, size_t ws_size,
                              hipStream_t stream) {
    const float* x       = (const float*)d_in[0];
    const float* ltp     = (const float*)d_in[1];
    const float* conv1_w = (const float*)d_in[2];
    const float* conv1_b = (const float*)d_in[3];
    const float* conv2_w = (const float*)d_in[4];
    const float* conv2_b = (const float*)d_in[5];
    const float* fc1_w   = (const float*)d_in[6];
    const float* fc1_b   = (const float*)d_in[7];
    const float* fc2_w   = (const float*)d_in[8];
    const float* fc2_b   = (const float*)d_in[9];
    float* out = (float*)d_out;

    const int do_pack = (ws_size >= WS_NEEDED) ? 1 : 0;

    float* wsum  = (float*)d_ws;                  // B*6*25
    float* wt_ws = wsum + Bn * C1 * 25;           // B*2
    u16*   x4b   = (u16*)(wt_ws + Bn * 2);        // 8B-aligned

    hipMemsetAsync(d_ws, 0, (size_t)WSUM_FLOATS * sizeof(float), stream);

    k1_fused<<<dim3((P1 + RPB - 1) / RPB, Bn), dim3(512), 0, stream>>>(
        x, conv1_w, conv1_b, wsum, x4b, do_pack);
    k2_head<<<dim3(Bn), dim3(64), 0, stream>>>(wsum, conv2_w, conv2_b,
                                               fc1_w, fc1_b, fc2_w, fc2_b,
                                               wt_ws, out);
    if (do_pack)
        k3_sample_pool_bf16<<<dim3(Hh * Bn), dim3(Wg), 0, stream>>>(x4b, ltp, wt_ws, out);
    else
        k3_sample_pool_nchw<<<dim3(Hh * Bn), dim3(Wg), 0, stream>>>(x, ltp, wt_ws, out);
}

// Round 6
// 184.438 us; speedup vs baseline: 2.9764x; 1.0879x over previous
//
#include <hip/hip_runtime.h>
#include <math.h>

// Problem constants
#define Bn    64
#define Cn    3
#define IMG   224
#define PLANE (IMG*IMG)      // 50176
#define C1    6
#define P1    110            // conv1(220) + maxpool2 -> 110
#define P2    106            // conv2 output spatial
#define NVALID (P2*P2)       // 11236
#define Hh    32
#define Ww    64
#define UPR   10
#define UPT   10
#define Hg    (Hh*UPR)       // 320
#define Wg    (Ww*UPT)       // 640
#define POOLED_SIZE (Bn*Cn*Hh*Ww)   // 393216
#define RPB   4              // pooled rows per block (1 per wave, 4 waves)
#define NCHUNK ((P1 + RPB - 1) / RPB)   // 28
#define PSTRIDE 152          // padded 150-float partial slot

typedef unsigned short u16;

// workspace: partials (B*28*152 f32) | wt (B*2 f32) | x4b (B*224*224*4 bf16)
#define PART_FLOATS ((size_t)Bn * NCHUNK * PSTRIDE)     // 272,384
#define X4B_U16     ((size_t)Bn * PLANE * 4)
#define WS_NEEDED   ((PART_FLOATS + Bn * 2) * 4 + X4B_U16 * 2)

__device__ __forceinline__ u16 f2bf(float f) {
    union { unsigned int u; float f; } c; c.f = f;
    unsigned int r = c.u + 0x7fffu + ((c.u >> 16) & 1u);   // RNE
    return (u16)(r >> 16);
}
__device__ __forceinline__ float bf2f(u16 v) {
    union { unsigned int u; float f; } c; c.u = ((unsigned int)v) << 16;
    return c.f;
}

// -------------------------------------------------------------------------
// K1: fused conv1 (all 6 OCs) + maxpool2 + bf16-NHWC4 repack + shuffle
// window sums -> deterministic per-block partial (150 floats) in ws.
// Block = 256 threads = 4 waves; wave wid handles pooled row y0+wid.
// Lane l (<55) computes pooled cols (2l, 2l+1) for all 6 OCs via a rolling
// 2-row register window. (RPB=4 proven best: RPB=8 regressed — R5.)
// -------------------------------------------------------------------------
__global__ __launch_bounds__(256) void k1_fused(
    const float* __restrict__ x,      // (B,3,224,224)
    const float* __restrict__ w1,     // (6,3,5,5)
    const float* __restrict__ b1,     // (6,)
    float* __restrict__ partial,      // (B,28,PSTRIDE)
    u16* __restrict__ x4b,            // (B,224,224,4) bf16 out
    int do_pack)
{
    __shared__ __attribute__((aligned(16))) float xs[3][12][224];  // 32256 B
    __shared__ float psum[RPB][PSTRIDE];                           // 2432 B

    const int b    = blockIdx.y;
    const int chunk = blockIdx.x;
    const int y0   = chunk * RPB;
    const int tid  = threadIdx.x;
    const int wid  = tid >> 6;
    const int lane = tid & 63;

    const float* xb = x + (size_t)b * (Cn * PLANE);
    const int gybase = 2 * y0;

    // stage 12 input rows x 3 ic, coalesced float4
    for (int i = tid; i < 3 * 12 * 56; i += 256) {
        const int ic  = i / (12 * 56);
        const int rem = i - ic * (12 * 56);
        const int r   = rem / 56;
        const int c4  = rem - r * 56;
        const int gy  = gybase + r;
        if (gy < IMG)
            *(float4*)(&xs[ic][r][c4 * 4]) =
                *(const float4*)(xb + ic * PLANE + gy * IMG + c4 * 4);
    }
    __syncthreads();

    // bf16 NHWC4 pack of this block's 8 owned rows (28 blocks x 8 = 224)
    if (do_pack) {
        u16* ob = x4b + (size_t)b * PLANE * 4;
        for (int i = tid; i < 8 * IMG; i += 256) {
            const int r   = i / IMG;
            const int col = i - r * IMG;
            const int gy  = gybase + r;
            ushort4 v;
            v.x = f2bf(xs[0][r][col]);
            v.y = f2bf(xs[1][r][col]);
            v.z = f2bf(xs[2][r][col]);
            v.w = 0;
            *(ushort4*)(ob + ((size_t)gy * IMG + col) * 4) = v;
        }
    }

    const int y = y0 + wid;
    const bool rowvalid = (y < P1);
    const bool active = (lane < 55) && rowvalid;

    float pp0[C1], pp1[C1];
    if (active) {
        float acc[C1][8];
        #pragma unroll
        for (int oc = 0; oc < C1; ++oc) {
            const float bv = b1[oc];
            #pragma unroll
            for (int j = 0; j < 8; ++j) acc[oc][j] = bv;
        }

        #pragma unroll
        for (int ic = 0; ic < 3; ++ic) {
            float rTop[8], rBot[8];
            {
                const float* rp = &xs[ic][2 * wid][4 * lane];
                const float4 a = *(const float4*)rp;
                const float4 c = *(const float4*)(rp + 4);
                rTop[0]=a.x; rTop[1]=a.y; rTop[2]=a.z; rTop[3]=a.w;
                rTop[4]=c.x; rTop[5]=c.y; rTop[6]=c.z; rTop[7]=c.w;
            }
            {
                const float* rp = &xs[ic][2 * wid + 1][4 * lane];
                const float4 a = *(const float4*)rp;
                const float4 c = *(const float4*)(rp + 4);
                rBot[0]=a.x; rBot[1]=a.y; rBot[2]=a.z; rBot[3]=a.w;
                rBot[4]=c.x; rBot[5]=c.y; rBot[6]=c.z; rBot[7]=c.w;
            }
            #pragma unroll
            for (int ky = 0; ky < 5; ++ky) {
                #pragma unroll
                for (int oc = 0; oc < C1; ++oc) {
                    const float* wrow = w1 + ((oc * 3 + ic) * 25 + ky * 5);
                    #pragma unroll
                    for (int kx = 0; kx < 5; ++kx) {
                        const float wv = wrow[kx];       // wave-uniform s_load
                        acc[oc][0] += rTop[kx    ] * wv;
                        acc[oc][1] += rTop[kx + 1] * wv;
                        acc[oc][2] += rTop[kx + 2] * wv;
                        acc[oc][3] += rTop[kx + 3] * wv;
                        acc[oc][4] += rBot[kx    ] * wv;
                        acc[oc][5] += rBot[kx + 1] * wv;
                        acc[oc][6] += rBot[kx + 2] * wv;
                        acc[oc][7] += rBot[kx + 3] * wv;
                    }
                }
                if (ky < 4) {
                    #pragma unroll
                    for (int j = 0; j < 8; ++j) rTop[j] = rBot[j];
                    const float* rp = &xs[ic][2 * wid + ky + 2][4 * lane];
                    const float4 a = *(const float4*)rp;
                    const float4 c = *(const float4*)(rp + 4);
                    rBot[0]=a.x; rBot[1]=a.y; rBot[2]=a.z; rBot[3]=a.w;
                    rBot[4]=c.x; rBot[5]=c.y; rBot[6]=c.z; rBot[7]=c.w;
                }
            }
        }

        #pragma unroll
        for (int oc = 0; oc < C1; ++oc) {
            pp0[oc] = fmaxf(fmaxf(acc[oc][0], acc[oc][1]),
                            fmaxf(acc[oc][4], acc[oc][5]));
            pp1[oc] = fmaxf(fmaxf(acc[oc][2], acc[oc][3]),
                            fmaxf(acc[oc][6], acc[oc][7]));
        }
    } else {
        #pragma unroll
        for (int oc = 0; oc < C1; ++oc) { pp0[oc] = 0.0f; pp1[oc] = 0.0f; }
    }

    // Wave-level windowed row sums -> psum[wid][oc*25 + ky*5 + kx].
    #pragma unroll
    for (int oc = 0; oc < C1; ++oc) {
        float s = pp0[oc] + pp1[oc];
        #pragma unroll
        for (int off = 32; off > 0; off >>= 1) s += __shfl_xor(s, off, 64);
        const float c0   = __shfl(pp0[oc], 0, 64);
        const float c1   = __shfl(pp1[oc], 0, 64);
        const float c2   = __shfl(pp0[oc], 1, 64);
        const float c3   = __shfl(pp1[oc], 1, 64);
        const float c106 = __shfl(pp0[oc], 53, 64);
        const float c107 = __shfl(pp1[oc], 53, 64);
        const float c108 = __shfl(pp0[oc], 54, 64);
        const float c109 = __shfl(pp1[oc], 54, 64);
        const float w0v = s - (c106 + c107 + c108 + c109);
        const float w1v = s - c0 - (c107 + c108 + c109);
        const float w2v = s - (c0 + c1) - (c108 + c109);
        const float w3v = s - (c0 + c1 + c2) - c109;
        const float w4v = s - (c0 + c1 + c2 + c3);
        if (lane < 25) {
            const int ky = lane / 5;
            const int kx = lane % 5;
            float wv = w0v;
            wv = (kx == 1) ? w1v : wv;
            wv = (kx == 2) ? w2v : wv;
            wv = (kx == 3) ? w3v : wv;
            wv = (kx == 4) ? w4v : wv;
            const bool valid = rowvalid && ((unsigned)(y - ky) <= 105u);
            psum[wid][oc * 25 + lane] = valid ? wv : 0.0f;
        }
    }
    __syncthreads();

    // Block reduce 4 waves -> per-block partial (deterministic, no atomics)
    if (tid < 150) {
        const float v = psum[0][tid] + psum[1][tid] + psum[2][tid] + psum[3][tid];
        partial[((size_t)b * NCHUNK + chunk) * PSTRIDE + tid] = v;
    }
}

// -------------------------------------------------------------------------
// K2: reduce partials -> wsum_b; feat = b2 + (W2 . wsum_b)/11236 ;
// fc1+relu ; fc2+sigmoid*5. One block (256 threads) per batch element.
// -------------------------------------------------------------------------
__global__ __launch_bounds__(256) void k2_head(
    const float* __restrict__ partial, const float* __restrict__ w2,
    const float* __restrict__ b2, const float* __restrict__ fc1w,
    const float* __restrict__ fc1b, const float* __restrict__ fc2w,
    const float* __restrict__ fc2b, float* __restrict__ wt_ws,
    float* __restrict__ out)
{
    const int b = blockIdx.x;
    const int tid = threadIdx.x;
    __shared__ float wsb[150];
    __shared__ float sfeat[16];
    __shared__ float sh[8];

    if (tid < 150) {
        const float* p = partial + (size_t)b * NCHUNK * PSTRIDE + tid;
        float s = 0.0f;
        #pragma unroll
        for (int c = 0; c < NCHUNK; ++c) s += p[c * PSTRIDE];
        wsb[tid] = s;
    }
    __syncthreads();
    if (tid < 16) {
        float s = 0.0f;
        for (int j = 0; j < 150; ++j) s += w2[tid * 150 + j] * wsb[j];
        sfeat[tid] = b2[tid] + s * (1.0f / (float)NVALID);
    }
    __syncthreads();
    if (tid < 8) {
        float s = fc1b[tid];
        #pragma unroll
        for (int j = 0; j < 16; ++j) s += fc1w[tid * 16 + j] * sfeat[j];
        sh[tid] = fmaxf(s, 0.0f);
    }
    __syncthreads();
    if (tid < 2) {
        float s = fc2b[tid];
        #pragma unroll
        for (int j = 0; j < 8; ++j) s += fc2w[tid * 8 + j] * sh[j];
        float sig = (s >= 0.0f) ? (1.0f / (1.0f + expf(-s)))
                                : (expf(s) / (1.0f + expf(s)));
        const float wgt = 5.0f * sig;
        wt_ws[b * 2 + tid] = wgt;
        out[POOLED_SIZE + b * 2 + tid] = wgt;
    }
}

// -------------------------------------------------------------------------
// Clamp-coordinate sampling (equivalent to corner-clamp border mode).
// -------------------------------------------------------------------------
__device__ __forceinline__ void sample_coords(
    float gxn, float gyn, int& x0, int& y0, float& wx, float& wy)
{
    float ix = ((gxn + 1.0f) * (float)IMG - 1.0f) * 0.5f;
    float iy = ((gyn + 1.0f) * (float)IMG - 1.0f) * 0.5f;
    ix = fminf(fmaxf(ix, 0.0f), (float)(IMG - 1));
    iy = fminf(fmaxf(iy, 0.0f), (float)(IMG - 1));
    x0 = (int)ix; if (x0 > IMG - 2) x0 = IMG - 2;
    y0 = (int)iy; if (y0 > IMG - 2) y0 = IMG - 2;
    wx = ix - (float)x0;
    wy = iy - (float)y0;
}

// -------------------------------------------------------------------------
// K3 (bf16 NHWC4): log-polar grid sample + 10x10 avg pool.
// XCD-affinity swizzle (R5 win): b = (L&7) + 8*(L>>8) so one XCD serves 8
// images (3.2 MB <= 4 MB L2) and walks each image's h-blocks consecutively.
// -------------------------------------------------------------------------
__global__ __launch_bounds__(640) void k3_sample_pool_bf16(
    const u16* __restrict__ x4b,      // (B,224,224,4) bf16
    const float* __restrict__ ltp,
    const float* __restrict__ wt,
    float* __restrict__ out)
{
    __shared__ float part[3 * Wg];

    const int L = blockIdx.x;         // 0..2047
    const int q = L >> 3;             // 0..255
    const int h = q & 31;
    const int b = (L & 7) + 8 * (q >> 5);
    const int tid = threadIdx.x;

    const float w0 = wt[b * 2 + 0];
    const float w1 = wt[b * 2 + 1];
    const float l0 = ltp[b * 2 + 0];
    const float l1 = ltp[b * 2 + 1];
    const float start = logf(0.01f * w0);
    const float stop  = logf(0.6f  * w1);
    const float dr = stop - start;

    const float angle = 6.283185307179586f * (float)tid / (float)Wg;
    const float sn = sinf(angle);
    const float cs = cosf(angle);

    const u16* xb4 = x4b + (size_t)b * PLANE * 4;

    const float ratio = expf(dr * (1.0f / (float)(Hg - 1)));
    float r = expf(start + dr * ((float)(h * UPR) / (float)(Hg - 1)));

    float acc0 = 0.0f, acc1 = 0.0f, acc2 = 0.0f;
    #pragma unroll
    for (int i = 0; i < UPR; ++i) {
        int x0, y0; float wx, wy;
        sample_coords(r * sn + l0, r * cs + l1, x0, y0, wx, wy);
        r *= ratio;

        const u16* base = xb4 + ((size_t)(y0 * IMG + x0)) * 4;
        const ushort4 a00 = *(const ushort4*)(base);
        const ushort4 a01 = *(const ushort4*)(base + 4);
        const ushort4 a10 = *(const ushort4*)(base + IMG * 4);
        const ushort4 a11 = *(const ushort4*)(base + IMG * 4 + 4);

        const float wx0 = 1.0f - wx, wy0 = 1.0f - wy;
        const float w00 = wx0 * wy0, w01 = wx * wy0;
        const float w10 = wx0 * wy,  w11 = wx * wy;

        acc0 += w00*bf2f(a00.x) + w01*bf2f(a01.x) + w10*bf2f(a10.x) + w11*bf2f(a11.x);
        acc1 += w00*bf2f(a00.y) + w01*bf2f(a01.y) + w10*bf2f(a10.y) + w11*bf2f(a11.y);
        acc2 += w00*bf2f(a00.z) + w01*bf2f(a01.z) + w10*bf2f(a10.z) + w11*bf2f(a11.z);
    }
    part[0 * Wg + tid] = acc0;
    part[1 * Wg + tid] = acc1;
    part[2 * Wg + tid] = acc2;
    __syncthreads();

    if (tid < Cn * Ww) {
        const int c = tid / Ww;
        const int w = tid % Ww;
        const float* p = part + c * Wg + w * UPT;
        float s = 0.0f;
        #pragma unroll
        for (int j = 0; j < UPT; ++j) s += p[j];
        out[(((size_t)b * Cn + c) * Hh + h) * Ww + w] = s * (1.0f / (UPR * UPT));
    }
}

// -------------------------------------------------------------------------
// K3 fallback (NCHW fp32 scalar gathers) — only if ws too small for x4b.
// -------------------------------------------------------------------------
__global__ __launch_bounds__(640) void k3_sample_pool_nchw(
    const float* __restrict__ x, const float* __restrict__ ltp,
    const float* __restrict__ wt, float* __restrict__ out)
{
    __shared__ float part[3 * Wg];
    const int L = blockIdx.x;
    const int q = L >> 3;
    const int h = q & 31;
    const int b = (L & 7) + 8 * (q >> 5);
    const int tid = threadIdx.x;

    const float w0 = wt[b * 2 + 0];
    const float w1 = wt[b * 2 + 1];
    const float l0 = ltp[b * 2 + 0];
    const float l1 = ltp[b * 2 + 1];
    const float start = logf(0.01f * w0);
    const float stop  = logf(0.6f  * w1);
    const float dr = stop - start;
    const float angle = 6.283185307179586f * (float)tid / (float)Wg;
    const float sn = sinf(angle);
    const float cs = cosf(angle);
    const float* xb = x + (size_t)b * Cn * PLANE;

    const float ratio = expf(dr * (1.0f / (float)(Hg - 1)));
    float r = expf(start + dr * ((float)(h * UPR) / (float)(Hg - 1)));

    float acc0 = 0.0f, acc1 = 0.0f, acc2 = 0.0f;
    #pragma unroll
    for (int i = 0; i < UPR; ++i) {
        int x0, y0; float wx, wy;
        sample_coords(r * sn + l0, r * cs + l1, x0, y0, wx, wy);
        r *= ratio;
        const float wx0 = 1.0f - wx, wy0 = 1.0f - wy;
        const float w00 = wx0 * wy0, w01 = wx * wy0;
        const float w10 = wx0 * wy,  w11 = wx * wy;
        const int o00 = y0 * IMG + x0;
        acc0 += w00*xb[o00] + w01*xb[o00+1] + w10*xb[o00+IMG] + w11*xb[o00+IMG+1];
        const float* x1p = xb + PLANE;
        acc1 += w00*x1p[o00] + w01*x1p[o00+1] + w10*x1p[o00+IMG] + w11*x1p[o00+IMG+1];
        const float* x2p = xb + 2 * PLANE;
        acc2 += w00*x2p[o00] + w01*x2p[o00+1] + w10*x2p[o00+IMG] + w11*x2p[o00+IMG+1];
    }
    part[0 * Wg + tid] = acc0;
    part[1 * Wg + tid] = acc1;
    part[2 * Wg + tid] = acc2;
    __syncthreads();

    if (tid < Cn * Ww) {
        const int c = tid / Ww;
        const int w = tid % Ww;
        const float* p = part + c * Wg + w * UPT;
        float s = 0.0f;
        #pragma unroll
        for (int j = 0; j < UPT; ++j) s += p[j];
        out[(((size_t)b * Cn + c) * Hh + h) * Ww + w] = s * (1.0f / (UPR * UPT));
    }
}

// -------------------------------------------------------------------------
extern "C" void kernel_launch(void* const* d_in, const int* in_sizes, int n_in,
                              void* d_out, int out_size, void* d_ws, size_t ws_size,
                              hipStream_t stream) {
    const float* x       = (const float*)d_in[0];
    const float* ltp     = (const float*)d_in[1];
    const float* conv1_w = (const float*)d_in[2];
    const float* conv1_b = (const float*)d_in[3];
    const float* conv2_w = (const float*)d_in[4];
    const float* conv2_b = (const float*)d_in[5];
    const float* fc1_w   = (const float*)d_in[6];
    const float* fc1_b   = (const float*)d_in[7];
    const float* fc2_w   = (const float*)d_in[8];
    const float* fc2_b   = (const float*)d_in[9];
    float* out = (float*)d_out;

    const int do_pack = (ws_size >= WS_NEEDED) ? 1 : 0;

    float* part_ws = (float*)d_ws;                // B*28*PSTRIDE
    float* wt_ws   = part_ws + PART_FLOATS;       // B*2
    u16*   x4b     = (u16*)(wt_ws + Bn * 2);      // 8B-aligned

    k1_fused<<<dim3(NCHUNK, Bn), dim3(256), 0, stream>>>(
        x, conv1_w, conv1_b, part_ws, x4b, do_pack);
    k2_head<<<dim3(Bn), dim3(256), 0, stream>>>(part_ws, conv2_w, conv2_b,
                                                fc1_w, fc1_b, fc2_w, fc2_b,
                                                wt_ws, out);
    if (do_pack)
        k3_sample_pool_bf16<<<dim3(Hh * Bn), dim3(Wg), 0, stream>>>(x4b, ltp, wt_ws, out);
    else
        k3_sample_pool_nchw<<<dim3(Hh * Bn), dim3(Wg), 0, stream>>>(x, ltp, wt_ws, out);
}

// Round 7
// 176.268 us; speedup vs baseline: 3.1143x; 1.0463x over previous
//
#include <hip/hip_runtime.h>
#include <math.h>

// Problem constants
#define Bn    64
#define Cn    3
#define IMG   224
#define PLANE (IMG*IMG)      // 50176
#define C1    6
#define P1    110            // conv1(220) + maxpool2 -> 110
#define P2    106            // conv2 output spatial
#define NVALID (P2*P2)       // 11236
#define Hh    32
#define Ww    64
#define UPR   10
#define UPT   10
#define Hg    (Hh*UPR)       // 320
#define Wg    (Ww*UPT)       // 640
#define POOLED_SIZE (Bn*Cn*Hh*Ww)   // 393216
#define RPB   4              // pooled rows per chunk (1 per wave, 4 waves)
#define NCHUNK ((P1 + RPB - 1) / RPB)   // 28
#define PSTRIDE 152          // padded 150-float partial slot

typedef unsigned short u16;
typedef float v2f __attribute__((ext_vector_type(2)));

// workspace: partials (B*28*152 f32) | wt (B*2 f32) | x4b (B*224*224*4 bf16)
#define PART_FLOATS ((size_t)Bn * NCHUNK * PSTRIDE)     // 272,384
#define X4B_U16     ((size_t)Bn * PLANE * 4)
#define WS_NEEDED   ((PART_FLOATS + Bn * 2) * 4 + X4B_U16 * 2)

__device__ __forceinline__ u16 f2bf(float f) {
    union { unsigned int u; float f; } c; c.f = f;
    unsigned int r = c.u + 0x7fffu + ((c.u >> 16) & 1u);   // RNE
    return (u16)(r >> 16);
}
__device__ __forceinline__ float bf2f(u16 v) {
    union { unsigned int u; float f; } c; c.u = ((unsigned int)v) << 16;
    return c.f;
}

// 7 overlapping pairs P[j] = (r[j], r[j+1]) from an 8-float LDS row segment.
// 4 of the 7 are the natural aligned pairs of the two b128 loads; the 3 odd
// ones cost movs. Feeds v_pk_fma_f32.
__device__ __forceinline__ void load_pairs(v2f* P, const float* rp) {
    const float4 a = *(const float4*)rp;
    const float4 c = *(const float4*)(rp + 4);
    P[0] = (v2f){a.x, a.y};
    P[1] = (v2f){a.y, a.z};
    P[2] = (v2f){a.z, a.w};
    P[3] = (v2f){a.w, c.x};
    P[4] = (v2f){c.x, c.y};
    P[5] = (v2f){c.y, c.z};
    P[6] = (v2f){c.z, c.w};
}

// -------------------------------------------------------------------------
// K1: fused conv1 (all 6 OCs, packed-fp32) + maxpool2 + bf16-NHWC4 repack +
// shuffle window sums -> deterministic per-block partials.
// Grid (14,64): each block processes chunks 2q, 2q+1 sequentially so the
// 896 blocks fit in one co-resident round (4 blocks/CU x 256 CUs) - no tail.
// Block = 256 threads = 4 waves; wave wid handles pooled row y0+wid.
// -------------------------------------------------------------------------
__global__ __launch_bounds__(256) void k1_fused(
    const float* __restrict__ x,      // (B,3,224,224)
    const float* __restrict__ w1,     // (6,3,5,5)
    const float* __restrict__ b1,     // (6,)
    float* __restrict__ partial,      // (B,28,PSTRIDE)
    u16* __restrict__ x4b,            // (B,224,224,4) bf16 out
    int do_pack)
{
    __shared__ __attribute__((aligned(16))) float xs[3][12][224];  // 32256 B
    __shared__ float psum[RPB][PSTRIDE];                           // 2432 B

    const int b    = blockIdx.y;
    const int tid  = threadIdx.x;
    const int wid  = tid >> 6;
    const int lane = tid & 63;

    const float* xb = x + (size_t)b * (Cn * PLANE);

    for (int half = 0; half < 2; ++half) {
        const int chunk = 2 * blockIdx.x + half;
        const int y0 = chunk * RPB;
        const int gybase = 2 * y0;

        // stage 12 input rows x 3 ic, coalesced float4
        for (int i = tid; i < 3 * 12 * 56; i += 256) {
            const int ic  = i / (12 * 56);
            const int rem = i - ic * (12 * 56);
            const int r   = rem / 56;
            const int c4  = rem - r * 56;
            const int gy  = gybase + r;
            if (gy < IMG)
                *(float4*)(&xs[ic][r][c4 * 4]) =
                    *(const float4*)(xb + ic * PLANE + gy * IMG + c4 * 4);
        }
        __syncthreads();

        // bf16 NHWC4 pack of this chunk's 8 owned rows (28 chunks x 8 = 224)
        if (do_pack) {
            u16* ob = x4b + (size_t)b * PLANE * 4;
            for (int i = tid; i < 8 * IMG; i += 256) {
                const int r   = i / IMG;
                const int col = i - r * IMG;
                const int gy  = gybase + r;
                ushort4 v;
                v.x = f2bf(xs[0][r][col]);
                v.y = f2bf(xs[1][r][col]);
                v.z = f2bf(xs[2][r][col]);
                v.w = 0;
                *(ushort4*)(ob + ((size_t)gy * IMG + col) * 4) = v;
            }
        }

        const int y = y0 + wid;
        const bool rowvalid = (y < P1);
        const bool active = (lane < 55) && rowvalid;

        float pp0[C1], pp1[C1];
        if (active) {
            // v2f accumulators: T=conv row 2y, B=conv row 2y+1;
            // 01 = cols (4l,4l+1), 23 = cols (4l+2,4l+3)
            v2f accT01[C1], accT23[C1], accB01[C1], accB23[C1];
            #pragma unroll
            for (int oc = 0; oc < C1; ++oc) {
                const float bv = b1[oc];
                const v2f bvv = (v2f){bv, bv};
                accT01[oc] = bvv; accT23[oc] = bvv;
                accB01[oc] = bvv; accB23[oc] = bvv;
            }

            #pragma unroll
            for (int ic = 0; ic < 3; ++ic) {
                v2f Pa[7], Pb[7];
                load_pairs(Pa, &xs[ic][2 * wid][4 * lane]);
                load_pairs(Pb, &xs[ic][2 * wid + 1][4 * lane]);
                #pragma unroll
                for (int ky = 0; ky < 5; ++ky) {
                    const v2f* Pt = (ky & 1) ? Pb : Pa;   // row 2y+ky
                    const v2f* Po = (ky & 1) ? Pa : Pb;   // row 2y+ky+1
                    #pragma unroll
                    for (int oc = 0; oc < C1; ++oc) {
                        const float* wrow = w1 + ((oc * 3 + ic) * 25 + ky * 5);
                        #pragma unroll
                        for (int kx = 0; kx < 5; ++kx) {
                            const float wv = wrow[kx];     // uniform s_load
                            const v2f wvv = (v2f){wv, wv};
                            accT01[oc] += Pt[kx]     * wvv;  // v_pk_fma_f32
                            accT23[oc] += Pt[kx + 2] * wvv;
                            accB01[oc] += Po[kx]     * wvv;
                            accB23[oc] += Po[kx + 2] * wvv;
                        }
                    }
                    if (ky < 4)
                        load_pairs((ky & 1) ? Pb : Pa,
                                   &xs[ic][2 * wid + ky + 2][4 * lane]);
                }
            }

            #pragma unroll
            for (int oc = 0; oc < C1; ++oc) {
                pp0[oc] = fmaxf(fmaxf(accT01[oc].x, accT01[oc].y),
                                fmaxf(accB01[oc].x, accB01[oc].y));
                pp1[oc] = fmaxf(fmaxf(accT23[oc].x, accT23[oc].y),
                                fmaxf(accB23[oc].x, accB23[oc].y));
            }
        } else {
            #pragma unroll
            for (int oc = 0; oc < C1; ++oc) { pp0[oc] = 0.0f; pp1[oc] = 0.0f; }
        }

        // Wave-level windowed row sums -> psum[wid][oc*25 + ky*5 + kx].
        #pragma unroll
        for (int oc = 0; oc < C1; ++oc) {
            float s = pp0[oc] + pp1[oc];
            #pragma unroll
            for (int off = 32; off > 0; off >>= 1) s += __shfl_xor(s, off, 64);
            const float c0   = __shfl(pp0[oc], 0, 64);
            const float c1   = __shfl(pp1[oc], 0, 64);
            const float c2   = __shfl(pp0[oc], 1, 64);
            const float c3   = __shfl(pp1[oc], 1, 64);
            const float c106 = __shfl(pp0[oc], 53, 64);
            const float c107 = __shfl(pp1[oc], 53, 64);
            const float c108 = __shfl(pp0[oc], 54, 64);
            const float c109 = __shfl(pp1[oc], 54, 64);
            const float w0v = s - (c106 + c107 + c108 + c109);
            const float w1v = s - c0 - (c107 + c108 + c109);
            const float w2v = s - (c0 + c1) - (c108 + c109);
            const float w3v = s - (c0 + c1 + c2) - c109;
            const float w4v = s - (c0 + c1 + c2 + c3);
            if (lane < 25) {
                const int ky = lane / 5;
                const int kx = lane % 5;
                float wv = w0v;
                wv = (kx == 1) ? w1v : wv;
                wv = (kx == 2) ? w2v : wv;
                wv = (kx == 3) ? w3v : wv;
                wv = (kx == 4) ? w4v : wv;
                const bool valid = rowvalid && ((unsigned)(y - ky) <= 105u);
                psum[wid][oc * 25 + lane] = valid ? wv : 0.0f;
            }
        }
        __syncthreads();

        // Block reduce 4 waves -> per-chunk partial (deterministic)
        if (tid < 150) {
            const float v = psum[0][tid] + psum[1][tid] + psum[2][tid] + psum[3][tid];
            partial[((size_t)b * NCHUNK + chunk) * PSTRIDE + tid] = v;
        }
        // next iteration's staging barrier orders xs rewrite after all reads
    }
}

// -------------------------------------------------------------------------
// K2: reduce partials -> wsum_b; feat = b2 + (W2 . wsum_b)/11236 ;
// fc1+relu ; fc2+sigmoid*5. One block (256 threads) per batch element.
// -------------------------------------------------------------------------
__global__ __launch_bounds__(256) void k2_head(
    const float* __restrict__ partial, const float* __restrict__ w2,
    const float* __restrict__ b2, const float* __restrict__ fc1w,
    const float* __restrict__ fc1b, const float* __restrict__ fc2w,
    const float* __restrict__ fc2b, float* __restrict__ wt_ws,
    float* __restrict__ out)
{
    const int b = blockIdx.x;
    const int tid = threadIdx.x;
    __shared__ float wsb[150];
    __shared__ float sfeat[16];
    __shared__ float sh[8];

    if (tid < 150) {
        const float* p = partial + (size_t)b * NCHUNK * PSTRIDE + tid;
        float s = 0.0f;
        #pragma unroll
        for (int c = 0; c < NCHUNK; ++c) s += p[c * PSTRIDE];
        wsb[tid] = s;
    }
    __syncthreads();
    if (tid < 16) {
        float s = 0.0f;
        for (int j = 0; j < 150; ++j) s += w2[tid * 150 + j] * wsb[j];
        sfeat[tid] = b2[tid] + s * (1.0f / (float)NVALID);
    }
    __syncthreads();
    if (tid < 8) {
        float s = fc1b[tid];
        #pragma unroll
        for (int j = 0; j < 16; ++j) s += fc1w[tid * 16 + j] * sfeat[j];
        sh[tid] = fmaxf(s, 0.0f);
    }
    __syncthreads();
    if (tid < 2) {
        float s = fc2b[tid];
        #pragma unroll
        for (int j = 0; j < 8; ++j) s += fc2w[tid * 8 + j] * sh[j];
        float sig = (s >= 0.0f) ? (1.0f / (1.0f + expf(-s)))
                                : (expf(s) / (1.0f + expf(s)));
        const float wgt = 5.0f * sig;
        wt_ws[b * 2 + tid] = wgt;
        out[POOLED_SIZE + b * 2 + tid] = wgt;
    }
}

// -------------------------------------------------------------------------
// Clamp-coordinate sampling (equivalent to corner-clamp border mode).
// -------------------------------------------------------------------------
__device__ __forceinline__ void sample_coords(
    float gxn, float gyn, int& x0, int& y0, float& wx, float& wy)
{
    float ix = ((gxn + 1.0f) * (float)IMG - 1.0f) * 0.5f;
    float iy = ((gyn + 1.0f) * (float)IMG - 1.0f) * 0.5f;
    ix = fminf(fmaxf(ix, 0.0f), (float)(IMG - 1));
    iy = fminf(fmaxf(iy, 0.0f), (float)(IMG - 1));
    x0 = (int)ix; if (x0 > IMG - 2) x0 = IMG - 2;
    y0 = (int)iy; if (y0 > IMG - 2) y0 = IMG - 2;
    wx = ix - (float)x0;
    wy = iy - (float)y0;
}

// -------------------------------------------------------------------------
// K3 (bf16 NHWC4): log-polar grid sample + 10x10 avg pool.
// XCD-affinity swizzle (R5 win): b = (L&7) + 8*(L>>8) so one XCD serves 8
// images (3.2 MB <= 4 MB L2) and walks each image's h-blocks consecutively.
// -------------------------------------------------------------------------
__global__ __launch_bounds__(640) void k3_sample_pool_bf16(
    const u16* __restrict__ x4b,      // (B,224,224,4) bf16
    const float* __restrict__ ltp,
    const float* __restrict__ wt,
    float* __restrict__ out)
{
    __shared__ float part[3 * Wg];

    const int L = blockIdx.x;         // 0..2047
    const int q = L >> 3;             // 0..255
    const int h = q & 31;
    const int b = (L & 7) + 8 * (q >> 5);
    const int tid = threadIdx.x;

    const float w0 = wt[b * 2 + 0];
    const float w1 = wt[b * 2 + 1];
    const float l0 = ltp[b * 2 + 0];
    const float l1 = ltp[b * 2 + 1];
    const float start = logf(0.01f * w0);
    const float stop  = logf(0.6f  * w1);
    const float dr = stop - start;

    const float angle = 6.283185307179586f * (float)tid / (float)Wg;
    const float sn = sinf(angle);
    const float cs = cosf(angle);

    const u16* xb4 = x4b + (size_t)b * PLANE * 4;

    const float ratio = expf(dr * (1.0f / (float)(Hg - 1)));
    float r = expf(start + dr * ((float)(h * UPR) / (float)(Hg - 1)));

    float acc0 = 0.0f, acc1 = 0.0f, acc2 = 0.0f;
    #pragma unroll
    for (int i = 0; i < UPR; ++i) {
        int x0, y0; float wx, wy;
        sample_coords(r * sn + l0, r * cs + l1, x0, y0, wx, wy);
        r *= ratio;

        const u16* base = xb4 + ((size_t)(y0 * IMG + x0)) * 4;
        const ushort4 a00 = *(const ushort4*)(base);
        const ushort4 a01 = *(const ushort4*)(base + 4);
        const ushort4 a10 = *(const ushort4*)(base + IMG * 4);
        const ushort4 a11 = *(const ushort4*)(base + IMG * 4 + 4);

        const float wx0 = 1.0f - wx, wy0 = 1.0f - wy;
        const float w00 = wx0 * wy0, w01 = wx * wy0;
        const float w10 = wx0 * wy,  w11 = wx * wy;

        acc0 += w00*bf2f(a00.x) + w01*bf2f(a01.x) + w10*bf2f(a10.x) + w11*bf2f(a11.x);
        acc1 += w00*bf2f(a00.y) + w01*bf2f(a01.y) + w10*bf2f(a10.y) + w11*bf2f(a11.y);
        acc2 += w00*bf2f(a00.z) + w01*bf2f(a01.z) + w10*bf2f(a10.z) + w11*bf2f(a11.z);
    }
    part[0 * Wg + tid] = acc0;
    part[1 * Wg + tid] = acc1;
    part[2 * Wg + tid] = acc2;
    __syncthreads();

    if (tid < Cn * Ww) {
        const int c = tid / Ww;
        const int w = tid % Ww;
        const float* p = part + c * Wg + w * UPT;
        float s = 0.0f;
        #pragma unroll
        for (int j = 0; j < UPT; ++j) s += p[j];
        out[(((size_t)b * Cn + c) * Hh + h) * Ww + w] = s * (1.0f / (UPR * UPT));
    }
}

// -------------------------------------------------------------------------
// K3 fallback (NCHW fp32 scalar gathers) — only if ws too small for x4b.
// -------------------------------------------------------------------------
__global__ __launch_bounds__(640) void k3_sample_pool_nchw(
    const float* __restrict__ x, const float* __restrict__ ltp,
    const float* __restrict__ wt, float* __restrict__ out)
{
    __shared__ float part[3 * Wg];
    const int L = blockIdx.x;
    const int q = L >> 3;
    const int h = q & 31;
    const int b = (L & 7) + 8 * (q >> 5);
    const int tid = threadIdx.x;

    const float w0 = wt[b * 2 + 0];
    const float w1 = wt[b * 2 + 1];
    const float l0 = ltp[b * 2 + 0];
    const float l1 = ltp[b * 2 + 1];
    const float start = logf(0.01f * w0);
    const float stop  = logf(0.6f  * w1);
    const float dr = stop - start;
    const float angle = 6.283185307179586f * (float)tid / (float)Wg;
    const float sn = sinf(angle);
    const float cs = cosf(angle);
    const float* xb = x + (size_t)b * Cn * PLANE;

    const float ratio = expf(dr * (1.0f / (float)(Hg - 1)));
    float r = expf(start + dr * ((float)(h * UPR) / (float)(Hg - 1)));

    float acc0 = 0.0f, acc1 = 0.0f, acc2 = 0.0f;
    #pragma unroll
    for (int i = 0; i < UPR; ++i) {
        int x0, y0; float wx, wy;
        sample_coords(r * sn + l0, r * cs + l1, x0, y0, wx, wy);
        r *= ratio;
        const float wx0 = 1.0f - wx, wy0 = 1.0f - wy;
        const float w00 = wx0 * wy0, w01 = wx * wy0;
        const float w10 = wx0 * wy,  w11 = wx * wy;
        const int o00 = y0 * IMG + x0;
        acc0 += w00*xb[o00] + w01*xb[o00+1] + w10*xb[o00+IMG] + w11*xb[o00+IMG+1];
        const float* x1p = xb + PLANE;
        acc1 += w00*x1p[o00] + w01*x1p[o00+1] + w10*x1p[o00+IMG] + w11*x1p[o00+IMG+1];
        const float* x2p = xb + 2 * PLANE;
        acc2 += w00*x2p[o00] + w01*x2p[o00+1] + w10*x2p[o00+IMG] + w11*x2p[o00+IMG+1];
    }
    part[0 * Wg + tid] = acc0;
    part[1 * Wg + tid] = acc1;
    part[2 * Wg + tid] = acc2;
    __syncthreads();

    if (tid < Cn * Ww) {
        const int c = tid / Ww;
        const int w = tid % Ww;
        const float* p = part + c * Wg + w * UPT;
        float s = 0.0f;
        #pragma unroll
        for (int j = 0; j < UPT; ++j) s += p[j];
        out[(((size_t)b * Cn + c) * Hh + h) * Ww + w] = s * (1.0f / (UPR * UPT));
    }
}

// -------------------------------------------------------------------------
extern "C" void kernel_launch(void* const* d_in, const int* in_sizes, int n_in,
                              void* d_out, int out_size, void* d_ws, size_t ws_size,
                              hipStream_t stream) {
    const float* x       = (const float*)d_in[0];
    const float* ltp     = (const float*)d_in[1];
    const float* conv1_w = (const float*)d_in[2];
    const float* conv1_b = (const float*)d_in[3];
    const float* conv2_w = (const float*)d_in[4];
    const float* conv2_b = (const float*)d_in[5];
    const float* fc1_w   = (const float*)d_in[6];
    const float* fc1_b   = (const float*)d_in[7];
    const float* fc2_w   = (const float*)d_in[8];
    const float* fc2_b   = (const float*)d_in[9];
    float* out = (float*)d_out;

    const int do_pack = (ws_size >= WS_NEEDED) ? 1 : 0;

    float* part_ws = (float*)d_ws;                // B*28*PSTRIDE
    float* wt_ws   = part_ws + PART_FLOATS;       // B*2
    u16*   x4b     = (u16*)(wt_ws + Bn * 2);      // 8B-aligned

    k1_fused<<<dim3(NCHUNK / 2, Bn), dim3(256), 0, stream>>>(
        x, conv1_w, conv1_b, part_ws, x4b, do_pack);
    k2_head<<<dim3(Bn), dim3(256), 0, stream>>>(part_ws, conv2_w, conv2_b,
                                                fc1_w, fc1_b, fc2_w, fc2_b,
                                                wt_ws, out);
    if (do_pack)
        k3_sample_pool_bf16<<<dim3(Hh * Bn), dim3(Wg), 0, stream>>>(x4b, ltp, wt_ws, out);
    else
        k3_sample_pool_nchw<<<dim3(Hh * Bn), dim3(Wg), 0, stream>>>(x, ltp, wt_ws, out);
}